// Round 1
// baseline (1077.700 us; speedup 1.0000x reference)
//
#include <hip/hip_runtime.h>
#include <cstddef>

// Problem constants
#define NPTS 4096
#define CCH  128
#define KNN  9
#define GRP  4
#define BB   4
// workspace layout (float offsets)
#define OFF_XT    0u          // 2097152 floats  (also reused as zpre after k_attn)
#define OFF_XX    2097152u    // 16384
#define OFF_IDX   2113536u    // 147456 ints
#define OFF_O     2260992u    // 16384*296 = 4849664
#define OFF_Y     7110656u    // 2097152
#define OFF_GNP   9207808u    // 131072
#define OFF_GNA   9338880u    // 512
#define OFF_GND   9339392u    // 512
#define OFF_WP    9339904u    // 65536
#define OFF_BIASP 9405440u    // 512
#define OFF_BNSUM 9405952u    // 128
#define OFF_BNSQ  9406080u    // 128
#define OFF_BNSC  9406208u    // 128
#define OFF_BNSH  9406336u    // 128

// ---------------- K1: transpose [B,C,N] -> xt [B*N, C]  + xx = sum_c x^2 ----------------
__global__ void k_transpose(const float* __restrict__ x, float* __restrict__ xt,
                            float* __restrict__ xx) {
  __shared__ float t[32][33];
  int tx = threadIdx.x, ty = threadIdx.y;
  int n0 = blockIdx.x * 32, c0 = blockIdx.y * 32, b = blockIdx.z;
  float v = x[((size_t)b * CCH + c0 + ty) * NPTS + n0 + tx];
  t[ty][tx] = v;
  __syncthreads();
  xt[((size_t)b * NPTS + n0 + ty) * CCH + c0 + tx] = t[tx][ty];
  if (ty == 0) {
    float s = 0.f;
    #pragma unroll
    for (int k = 0; k < 32; k++) { float u = t[k][tx]; s += u * u; }
    atomicAdd(&xx[b * NPTS + n0 + tx], s);
  }
}

// ---------------- K2: fused Gram + top-9 (per batch) ----------------
// block 256 (16x16), 64 rows/block, 64-col tiles, 4x4 reg tile, XOR-swizzled LDS.
__launch_bounds__(256, 1)
__global__ void k_knn(const float* __restrict__ xt, const float* __restrict__ xx,
                      int* __restrict__ idxOut) {
  __shared__ __align__(16) float smem[24576]; // rows 8192 | cols 2x8192 (96KB)
  float* rowsS  = smem;
  float* colsS0 = smem + 8192;
  float* colsS1 = smem + 16384;
  int tid = threadIdx.x;
  int tx = tid & 15, ty = tid >> 4;
  int b = blockIdx.y;
  int row0 = blockIdx.x * 64;
  const float* xb  = xt + (size_t)b * NPTS * CCH;
  const float* xxb = xx + b * NPTS;

  // stage rows tile (swizzled: slot q holds global c4 = q ^ (r&31))
  #pragma unroll
  for (int i = 0; i < 8; i++) {
    int flat = tid + i * 256; int r = flat >> 5, c4 = flat & 31;
    float4 v = *(const float4*)&xb[(size_t)(row0 + r) * CCH + c4 * 4];
    *(float4*)&rowsS[r * 128 + ((c4 ^ (r & 31)) * 4)] = v;
  }
  // stage cols tile 0
  #pragma unroll
  for (int i = 0; i < 8; i++) {
    int flat = tid + i * 256; int r = flat >> 5, c4 = flat & 31;
    float4 v = *(const float4*)&xb[(size_t)r * CCH + c4 * 4];
    *(float4*)&colsS0[r * 128 + ((c4 ^ (r & 31)) * 4)] = v;
  }
  __syncthreads();

  float tv[4][9]; int tix[4][9];
  #pragma unroll
  for (int i = 0; i < 4; i++)
    #pragma unroll
    for (int p = 0; p < 9; p++) { tv[i][p] = -3.4e38f; tix[i][p] = 0x7fffffff; }

  int rbase[4], rxor[4], cbase[4], cxor[4];
  #pragma unroll
  for (int i = 0; i < 4; i++) { int r = ty * 4 + i; rbase[i] = r * 128; rxor[i] = r & 31; }
  #pragma unroll
  for (int j = 0; j < 4; j++) { int m = tx + 16 * j; cbase[j] = m * 128; cxor[j] = m & 31; }

  for (int t = 0; t < 64; t++) {
    float* cur = (t & 1) ? colsS1 : colsS0;
    float* nxt = (t & 1) ? colsS0 : colsS1;
    float4 pf[8];
    if (t < 63) {
      const float* src = xb + (size_t)(t + 1) * 64 * CCH;
      #pragma unroll
      for (int i = 0; i < 8; i++) {
        int flat = tid + i * 256;
        pf[i] = *(const float4*)&src[(size_t)flat * 4];
      }
    }
    float acc[4][4] = {};
    #pragma unroll 2
    for (int kq = 0; kq < 32; kq++) {
      float4 ra[4], cb[4];
      #pragma unroll
      for (int i = 0; i < 4; i++) ra[i] = *(const float4*)&rowsS[rbase[i] + ((kq ^ rxor[i]) * 4)];
      #pragma unroll
      for (int j = 0; j < 4; j++) cb[j] = *(const float4*)&cur[cbase[j] + ((kq ^ cxor[j]) * 4)];
      #pragma unroll
      for (int i = 0; i < 4; i++)
        #pragma unroll
        for (int j = 0; j < 4; j++)
          acc[i][j] += ra[i].x * cb[j].x + ra[i].y * cb[j].y + ra[i].z * cb[j].z + ra[i].w * cb[j].w;
    }
    // top-9 candidate update: rank key = 2*inner - xx_m (same order as pd)
    #pragma unroll
    for (int j = 0; j < 4; j++) {
      int m2 = t * 64 + tx + 16 * j;
      float vxx = xxb[m2];
      #pragma unroll
      for (int i = 0; i < 4; i++) {
        float v = 2.f * acc[i][j] - vxx;
        if (v > tv[i][8]) {           // strict >: equal values keep earlier index
          float cv = v; int ci = m2;
          #pragma unroll
          for (int p = 0; p < 9; p++) {
            bool gt = cv > tv[i][p];
            float ov = tv[i][p]; int oi = tix[i][p];
            tv[i][p] = gt ? cv : ov; tix[i][p] = gt ? ci : oi;
            cv = gt ? ov : cv;       ci = gt ? oi : ci;
          }
        }
      }
    }
    if (t < 63) {
      #pragma unroll
      for (int i = 0; i < 8; i++) {
        int flat = tid + i * 256; int r = flat >> 5, c4 = flat & 31;
        *(float4*)&nxt[r * 128 + ((c4 ^ (r & 31)) * 4)] = pf[i];
      }
    }
    __syncthreads();
  }

  // merge 16 per-thread lists per row (reuse LDS)
  float* mv = smem;                 // [64][16][9]
  int*   mi = (int*)(smem + 9216);  // [64][16][9]
  #pragma unroll
  for (int i = 0; i < 4; i++) {
    int r = ty * 4 + i;
    #pragma unroll
    for (int p = 0; p < 9; p++) {
      mv[(r * 16 + tx) * 9 + p] = tv[i][p];
      mi[(r * 16 + tx) * 9 + p] = tix[i][p];
    }
  }
  __syncthreads();
  if (tid < 64) {
    float bv[9]; int bi[9];
    #pragma unroll
    for (int p = 0; p < 9; p++) { bv[p] = -3.4e38f; bi[p] = 0x7fffffff; }
    for (int s = 0; s < 16; s++) {
      #pragma unroll
      for (int p = 0; p < 9; p++) {
        float v = mv[(tid * 16 + s) * 9 + p];
        int   m2 = mi[(tid * 16 + s) * 9 + p];
        if ((v > bv[8]) || (v == bv[8] && m2 < bi[8])) {
          float cv = v; int ci = m2;
          #pragma unroll
          for (int q = 0; q < 9; q++) {
            bool gt = (cv > bv[q]) || (cv == bv[q] && ci < bi[q]);
            float ov = bv[q]; int oi = bi[q];
            bv[q] = gt ? cv : ov; bi[q] = gt ? ci : oi;
            cv = gt ? ov : cv;    ci = gt ? oi : ci;
          }
        }
      }
    }
    int rg = row0 + tid;
    #pragma unroll
    for (int p = 0; p < 9; p++) idxOut[(size_t)(b * NPTS + rg) * 9 + p] = bi[p];
  }
}

// ---------------- K3: O[pos][0:128]=u=(Wa+Wb)x+b_lin, [128:256]=v=Wb x, [256:292]=aw logits ----------------
__launch_bounds__(256)
__global__ void k_linear(const float* __restrict__ xt, const float* __restrict__ w_lin,
                         const float* __restrict__ b_lin, const float* __restrict__ w_aw,
                         const float* __restrict__ b_aw, float* __restrict__ O) {
  __shared__ __align__(16) float Xs[64 * 132];
  __shared__ __align__(16) float Ws[64 * 132];
  int tid = threadIdx.x;
  int tx = tid & 15, ty = tid >> 4;
  int p0 = blockIdx.x * 64, o0 = blockIdx.y * 64;
  #pragma unroll
  for (int i = 0; i < 8; i++) {
    int flat = tid + i * 256; int r = flat >> 5, c4 = flat & 31;
    *(float4*)&Xs[r * 132 + c4 * 4] = *(const float4*)&xt[(size_t)(p0 + r) * CCH + c4 * 4];
  }
  #pragma unroll
  for (int i = 0; i < 8; i++) {
    int flat = tid + i * 256; int r = flat >> 5, c4 = flat & 31;
    int o = o0 + r; float4 v;
    if (o < 128) {
      float4 a = *(const float4*)&w_lin[(size_t)o * 256 + c4 * 4];
      float4 c = *(const float4*)&w_lin[(size_t)o * 256 + 128 + c4 * 4];
      v = make_float4(a.x + c.x, a.y + c.y, a.z + c.z, a.w + c.w);
    } else if (o < 256) {
      v = *(const float4*)&w_lin[(size_t)(o - 128) * 256 + 128 + c4 * 4];
    } else if (o < 292) {
      v = *(const float4*)&w_aw[(size_t)(o - 256) * 128 + c4 * 4];
    } else v = make_float4(0.f, 0.f, 0.f, 0.f);
    *(float4*)&Ws[r * 132 + c4 * 4] = v;
  }
  __syncthreads();
  float acc[4][4] = {};
  #pragma unroll 2
  for (int kq = 0; kq < 32; kq++) {
    float4 xa[4], wb[4];
    #pragma unroll
    for (int i = 0; i < 4; i++) xa[i] = *(const float4*)&Xs[(ty * 4 + i) * 132 + kq * 4];
    #pragma unroll
    for (int j = 0; j < 4; j++) wb[j] = *(const float4*)&Ws[(tx + 16 * j) * 132 + kq * 4];
    #pragma unroll
    for (int i = 0; i < 4; i++)
      #pragma unroll
      for (int j = 0; j < 4; j++)
        acc[i][j] += xa[i].x * wb[j].x + xa[i].y * wb[j].y + xa[i].z * wb[j].z + xa[i].w * wb[j].w;
  }
  #pragma unroll
  for (int j = 0; j < 4; j++) {
    int o = o0 + tx + 16 * j;
    if (o < 292) {
      float bias = (o < 128) ? b_lin[o] : ((o < 256) ? 0.f : b_aw[o - 256]);
      #pragma unroll
      for (int i = 0; i < 4; i++)
        O[(size_t)(p0 + ty * 4 + i) * 296 + o] = acc[i][j] + bias;
    }
  }
}

// ---------------- K4: per-point grouped attention, residual, GN partials ----------------
__launch_bounds__(256)
__global__ void k_attn(const float* __restrict__ O, const int* __restrict__ idxArr,
                       const float* __restrict__ xt, float* __restrict__ Y,
                       float* __restrict__ gnPart) {
  __shared__ __align__(16) float fF[4][1188];
  __shared__ __align__(16) float fE[4][1188];
  __shared__ __align__(16) float scS[4][432];
  __shared__ float awS[4][48];
  __shared__ float w9S[4][48];
  __shared__ int tI[45], tJ[45];
  int tid = threadIdx.x;
  int wave = tid >> 6, l = tid & 63;
  int pos = blockIdx.x * 4 + wave;
  int b = pos >> 12;
  if (tid == 0) {
    int p = 0;
    for (int i = 0; i < 9; i++) for (int j = i; j < 9; j++) { tI[p] = i; tJ[p] = j; p++; }
  }
  int nbr[9];
  const float* Op = O + (size_t)pos * 296;
  #pragma unroll
  for (int k = 0; k < 9; k++) nbr[k] = idxArr[(size_t)pos * 9 + k];
  float2 u = *(const float2*)(Op + 2 * l);
  float* fFw = fF[wave];
  float* fEw = fE[wave];
  #pragma unroll
  for (int k = 0; k < 9; k++) {
    const float* vp = O + (size_t)((b << 12) + nbr[k]) * 296 + 128;
    float2 vv = *(const float2*)(vp + 2 * l);
    float f0 = u.x - vv.x, f1 = u.y - vv.y;
    fFw[k * 132 + 2 * l]     = f0;
    fFw[k * 132 + 2 * l + 1] = f1;
    fEw[k * 132 + 2 * l]     = f0 > 0.f ? f0 : __expf(f0) - 1.f;
    fEw[k * 132 + 2 * l + 1] = f1 > 0.f ? f1 : __expf(f1) - 1.f;
  }
  __syncthreads();
  // scores (upper triangle incl diag), written symmetric
  #pragma unroll
  for (int r = 0; r < 3; r++) {
    int p = r * 64 + l;
    if (p < 180) {
      int g = p / 45, q = p - g * 45;
      int i = tI[q], j = tJ[q];
      const float* fi = fFw + i * 132 + g * 32;
      const float* fj = fFw + j * 132 + g * 32;
      float s = 0.f;
      #pragma unroll
      for (int t8 = 0; t8 < 8; t8++) {
        float4 a4 = *(const float4*)(fi + 4 * t8);
        float4 b4 = *(const float4*)(fj + 4 * t8);
        s += a4.x * b4.x + a4.y * b4.y + a4.z * b4.z + a4.w * b4.w;
      }
      s *= 0.17677669529663687f; // 1/sqrt(32)
      scS[wave][(g * 9 + i) * 12 + j] = s;
      scS[wave][(g * 9 + j) * 12 + i] = s;
    }
  }
  __syncthreads();
  // row softmax (lanes 0..35) + aw softmax (lanes 36..39)
  if (l < 36) {
    int g = l / 9, i = l - g * 9;
    float* rp = &scS[wave][(g * 9 + i) * 12];
    float mx = rp[0];
    #pragma unroll
    for (int j = 1; j < 9; j++) mx = fmaxf(mx, rp[j]);
    float e[9]; float sm = 0.f;
    #pragma unroll
    for (int j = 0; j < 9; j++) { e[j] = __expf(rp[j] - mx); sm += e[j]; }
    float inv = 1.f / sm;
    #pragma unroll
    for (int j = 0; j < 9; j++) rp[j] = e[j] * inv;
  } else if (l < 40) {
    int g = l - 36;
    float a[9]; float mx = -3.4e38f;
    #pragma unroll
    for (int k = 0; k < 9; k++) { a[k] = Op[256 + g * 9 + k]; mx = fmaxf(mx, a[k]); }
    float sm = 0.f;
    #pragma unroll
    for (int k = 0; k < 9; k++) { a[k] = __expf(a[k] - mx); sm += a[k]; }
    float inv = 1.f / sm;
    #pragma unroll
    for (int k = 0; k < 9; k++) awS[wave][g * 12 + k] = a[k] * inv;
  }
  __syncthreads();
  // w9[g][j] = sum_k aw[g][k] * s[g][k][j]
  if (l < 36) {
    int g = l / 9, j = l - g * 9;
    float s = 0.f;
    #pragma unroll
    for (int i = 0; i < 9; i++) s += awS[wave][g * 12 + i] * scS[wave][(g * 9 + i) * 12 + j];
    w9S[wave][g * 12 + j] = s;
  }
  __syncthreads();
  // lf[c] = sum_j w9[g][j] * elu(feat[j][c]); y = lf + x; GN partials
  int g = l >> 4;
  float w9r[9];
  #pragma unroll
  for (int j = 0; j < 9; j++) w9r[j] = w9S[wave][g * 12 + j];
  int c0 = 2 * l;
  float lf0 = 0.f, lf1 = 0.f;
  #pragma unroll
  for (int j = 0; j < 9; j++) {
    lf0 += w9r[j] * fEw[j * 132 + c0];
    lf1 += w9r[j] * fEw[j * 132 + c0 + 1];
  }
  float2 xv = *(const float2*)(xt + (size_t)pos * CCH + c0);
  float y0 = lf0 + xv.x, y1 = lf1 + xv.y;
  *(float2*)(Y + (size_t)pos * CCH + c0) = make_float2(y0, y1);
  float s1 = y0 + y1, s2 = y0 * y0 + y1 * y1;
  #pragma unroll
  for (int m = 1; m <= 8; m <<= 1) { s1 += __shfl_xor(s1, m); s2 += __shfl_xor(s2, m); }
  if ((l & 15) == 0) {
    gnPart[(size_t)pos * 8 + g * 2]     = s1;
    gnPart[(size_t)pos * 8 + g * 2 + 1] = s2;
  }
}

// ---------------- K5: GN stats -> per (b,c) affine a,d ----------------
__global__ void k_gnstats(const float* __restrict__ gnPart,
                          const float* __restrict__ gn_g, const float* __restrict__ gn_b,
                          float* __restrict__ gnA, float* __restrict__ gnD) {
  int bg = blockIdx.x; int b = bg >> 2, g = bg & 3;
  int tid = threadIdx.x;
  float s1 = 0.f, s2 = 0.f;
  for (int r = tid; r < NPTS; r += 256) {
    const float* p = gnPart + (size_t)(b * NPTS + r) * 8 + g * 2;
    s1 += p[0]; s2 += p[1];
  }
  __shared__ float r1[256], r2[256];
  r1[tid] = s1; r2[tid] = s2;
  __syncthreads();
  for (int off = 128; off > 0; off >>= 1) {
    if (tid < off) { r1[tid] += r1[tid + off]; r2[tid] += r2[tid + off]; }
    __syncthreads();
  }
  __shared__ float muS, rsS;
  if (tid == 0) {
    float mu = r1[0] * (1.f / 131072.f);
    float var = r2[0] * (1.f / 131072.f) - mu * mu;
    muS = mu; rsS = 1.f / sqrtf(var + 1e-5f);
  }
  __syncthreads();
  if (tid < 32) {
    int c = g * 32 + tid;
    float a = rsS * gn_g[c];
    gnA[b * 128 + c] = a;
    gnD[b * 128 + c] = gn_b[c] - muS * a;
  }
}

// ---------------- K5b: fold GN affine into conv weights per batch ----------------
__global__ void k_fold(const float* __restrict__ conv_w, const float* __restrict__ conv_b,
                       const float* __restrict__ gnA, const float* __restrict__ gnD,
                       float* __restrict__ Wp, float* __restrict__ biasp) {
  int b = blockIdx.x; int tid = threadIdx.x;
  __shared__ float dS[128], aS[128];
  if (tid < 128) { dS[tid] = gnD[b * 128 + tid]; aS[tid] = gnA[b * 128 + tid]; }
  __syncthreads();
  for (int f = tid; f < 16384; f += 256)
    Wp[(size_t)b * 16384 + f] = conv_w[f] * aS[f & 127];
  if (tid < 128) {
    float s = conv_b[tid];
    for (int c = 0; c < 128; c++) s += conv_w[tid * 128 + c] * dS[c];
    biasp[b * 128 + tid] = s;
  }
}

// ---------------- K6: conv GEMM on raw y + BN partial sums ----------------
__launch_bounds__(256)
__global__ void k_conv(const float* __restrict__ Y, const float* __restrict__ Wp,
                       const float* __restrict__ biasp, float* __restrict__ zpre,
                       float* __restrict__ bnSum, float* __restrict__ bnSq) {
  __shared__ __align__(16) float Ys[64 * 132];
  __shared__ __align__(16) float Ws[64 * 132];
  int tid = threadIdx.x;
  int tx = tid & 15, ty = tid >> 4;
  int n0 = blockIdx.x * 64, o0 = blockIdx.y * 64, b = blockIdx.z;
  #pragma unroll
  for (int i = 0; i < 8; i++) {
    int flat = tid + i * 256; int r = flat >> 5, c4 = flat & 31;
    *(float4*)&Ys[r * 132 + c4 * 4] = *(const float4*)&Y[(size_t)((b << 12) + n0 + r) * CCH + c4 * 4];
    *(float4*)&Ws[r * 132 + c4 * 4] = *(const float4*)&Wp[(size_t)b * 16384 + (size_t)(o0 + r) * 128 + c4 * 4];
  }
  __syncthreads();
  float acc[4][4] = {};
  #pragma unroll 2
  for (int kq = 0; kq < 32; kq++) {
    float4 wa[4], yb[4];
    #pragma unroll
    for (int i = 0; i < 4; i++) wa[i] = *(const float4*)&Ws[(ty * 4 + i) * 132 + kq * 4];
    #pragma unroll
    for (int j = 0; j < 4; j++) yb[j] = *(const float4*)&Ys[(tx + 16 * j) * 132 + kq * 4];
    #pragma unroll
    for (int i = 0; i < 4; i++)
      #pragma unroll
      for (int j = 0; j < 4; j++)
        acc[i][j] += wa[i].x * yb[j].x + wa[i].y * yb[j].y + wa[i].z * yb[j].z + wa[i].w * yb[j].w;
  }
  #pragma unroll
  for (int i = 0; i < 4; i++) {
    int o = o0 + ty * 4 + i;
    float bias = biasp[b * 128 + o];
    float p1 = 0.f, p2 = 0.f;
    #pragma unroll
    for (int j = 0; j < 4; j++) {
      float z = acc[i][j] + bias;
      zpre[(((size_t)((b << 7) + o)) << 12) + n0 + tx + 16 * j] = z;
      p1 += z; p2 += z * z;
    }
    #pragma unroll
    for (int m = 1; m <= 8; m <<= 1) { p1 += __shfl_xor(p1, m); p2 += __shfl_xor(p2, m); }
    if (tx == 0) { atomicAdd(&bnSum[o], p1); atomicAdd(&bnSq[o], p2); }
  }
}

// ---------------- K7a: BN finalize ----------------
__global__ void k_bnfin(const float* __restrict__ bnSum, const float* __restrict__ bnSq,
                        const float* __restrict__ bn_g, const float* __restrict__ bn_b,
                        float* __restrict__ bnScale, float* __restrict__ bnShift) {
  int o = threadIdx.x;
  float m = bnSum[o] * (1.f / 16384.f);
  float v = bnSq[o] * (1.f / 16384.f) - m * m;
  float sc = bn_g[o] / sqrtf(v + 1e-5f);
  bnScale[o] = sc;
  bnShift[o] = bn_b[o] - m * sc;
}

// ---------------- K7b: normalize + ReLU -> d_out ----------------
__global__ void k_final(const float* __restrict__ zpre, const float* __restrict__ bnScale,
                        const float* __restrict__ bnShift, float* __restrict__ out) {
  int i4 = blockIdx.x * 256 + threadIdx.x;
  int e = i4 * 4;
  int o = (e >> 12) & 127;
  float4 z = *(const float4*)&zpre[e];
  float sc = bnScale[o], sh = bnShift[o];
  float4 r;
  r.x = fmaxf(fmaf(z.x, sc, sh), 0.f);
  r.y = fmaxf(fmaf(z.y, sc, sh), 0.f);
  r.z = fmaxf(fmaf(z.z, sc, sh), 0.f);
  r.w = fmaxf(fmaf(z.w, sc, sh), 0.f);
  *(float4*)&out[e] = r;
}

extern "C" void kernel_launch(void* const* d_in, const int* in_sizes, int n_in,
                              void* d_out, int out_size, void* d_ws, size_t ws_size,
                              hipStream_t stream) {
  const float* features = (const float*)d_in[0];
  const float* w_lin  = (const float*)d_in[1];
  const float* b_lin  = (const float*)d_in[2];
  const float* w_aw   = (const float*)d_in[3];
  const float* b_aw   = (const float*)d_in[4];
  const float* gn_g   = (const float*)d_in[5];
  const float* gn_b   = (const float*)d_in[6];
  const float* conv_w = (const float*)d_in[7];
  const float* conv_b = (const float*)d_in[8];
  const float* bn_g   = (const float*)d_in[9];
  const float* bn_b   = (const float*)d_in[10];

  float* ws    = (float*)d_ws;
  float* xt    = ws + OFF_XT;          // reused as zpre after k_attn
  float* xxp   = ws + OFF_XX;
  int*   idxp  = (int*)(ws + OFF_IDX);
  float* Op    = ws + OFF_O;
  float* Yp    = ws + OFF_Y;
  float* gnp   = ws + OFF_GNP;
  float* gnA   = ws + OFF_GNA;
  float* gnD   = ws + OFF_GND;
  float* Wp    = ws + OFF_WP;
  float* biasp = ws + OFF_BIASP;
  float* bnSum = ws + OFF_BNSUM;
  float* bnSq  = ws + OFF_BNSQ;
  float* bnSc  = ws + OFF_BNSC;
  float* bnSh  = ws + OFF_BNSH;
  float* zpre  = xt; // alias: xt dead after k_attn

  hipMemsetAsync(xxp, 0, NPTS * BB * sizeof(float), stream);
  hipMemsetAsync(bnSum, 0, 256 * sizeof(float), stream); // bnSum + bnSq contiguous

  k_transpose<<<dim3(128, 4, 4), dim3(32, 32), 0, stream>>>(features, xt, xxp);
  k_knn<<<dim3(64, 4), 256, 0, stream>>>(xt, xxp, idxp);
  k_linear<<<dim3(256, 5), 256, 0, stream>>>(xt, w_lin, b_lin, w_aw, b_aw, Op);
  k_attn<<<4096, 256, 0, stream>>>(Op, idxp, xt, Yp, gnp);
  k_gnstats<<<16, 256, 0, stream>>>(gnp, gn_g, gn_b, gnA, gnD);
  k_fold<<<4, 256, 0, stream>>>(conv_w, conv_b, gnA, gnD, Wp, biasp);
  k_conv<<<dim3(64, 2, 4), 256, 0, stream>>>(Yp, Wp, biasp, zpre, bnSum, bnSq);
  k_bnfin<<<1, 128, 0, stream>>>(bnSum, bnSq, bn_g, bn_b, bnSc, bnSh);
  k_final<<<2048, 256, 0, stream>>>(zpre, bnSc, bnSh, (float*)d_out);
}

// Round 2
// 461.361 us; speedup vs baseline: 2.3359x; 2.3359x over previous
//
#include <hip/hip_runtime.h>
#include <hip/hip_bf16.h>
#include <cstddef>

// Problem constants
#define NPTS 4096
#define CCH  128
#define KNN  9
#define GRP  4
#define BB   4
// workspace layout (float offsets)
#define OFF_XT    0u          // 2097152 floats (reused as zpre after k_attn)
#define OFF_XX    2097152u    // 16384
#define OFF_XHI   2113536u    // 1048576 float-slots = 2097152 bf16
#define OFF_IDX   3162112u    // 147456 ints
#define OFF_O     3309568u    // 4849664 (candbuf aliases first 4194304 floats)
#define OFF_Y     8159232u    // 2097152
#define OFF_GNP   10256384u   // 131072
#define OFF_GNA   10387456u   // 512
#define OFF_GND   10387968u   // 512
#define OFF_WP    10388480u   // 65536
#define OFF_BIASP 10454016u   // 512
#define OFF_BNSUM 10454528u   // 128
#define OFF_BNSQ  10454656u   // 128
#define OFF_BNSC  10454784u   // 128
#define OFF_BNSH  10454912u   // 128

using bf16x8 = __attribute__((ext_vector_type(8))) short;
using f32x4  = __attribute__((ext_vector_type(4))) float;

// ---------------- K1: transpose [B,C,N] -> xt [B*N,C] fp32 + xhi bf16 + xx ----------------
__global__ void k_transpose(const float* __restrict__ x, float* __restrict__ xt,
                            __hip_bfloat16* __restrict__ xhi, float* __restrict__ xx) {
  __shared__ float t[32][33];
  int tx = threadIdx.x, ty = threadIdx.y;
  int n0 = blockIdx.x * 32, c0 = blockIdx.y * 32, b = blockIdx.z;
  float v = x[((size_t)b * CCH + c0 + ty) * NPTS + n0 + tx];
  t[ty][tx] = v;
  __syncthreads();
  float tv = t[tx][ty];
  size_t oi = ((size_t)b * NPTS + n0 + ty) * CCH + c0 + tx;
  xt[oi] = tv;
  xhi[oi] = __float2bfloat16(tv);
  if (ty == 0) {
    float s = 0.f;
    #pragma unroll
    for (int k = 0; k < 32; k++) { float u = t[k][tx]; s += u * u; }
    atomicAdd(&xx[b * NPTS + n0 + tx], s);
  }
}

// ---------------- K2: MFMA Gram (bf16 hi) + fused per-lane top-8 ----------------
// Block: 256 thr = 4 waves, 32 queries (q-frags in regs), candidates in 128-chunks.
// D[cand][query] via mfma_f32_16x16x32_bf16: col=lane&15=query, row=quad*4+reg=cand.
// Rank key = 2*inner_bf16 - xx_m (exact fp32 xx). Per-lane top-8 -> cand lists.
__launch_bounds__(256, 2)
__global__ void k_knn(const short* __restrict__ xhi, const float* __restrict__ xx,
                      float2* __restrict__ cand) {
  __shared__ short Acs[128 * 128]; // 32 KB, 16B-granule XOR swizzle
  const int tid = threadIdx.x;
  const int wave = tid >> 6, lane = tid & 63;
  const int quad = lane >> 4, m = lane & 15;
  const int b = blockIdx.y;
  const int q0 = blockIdx.x * 32;
  const short* xb = xhi + (size_t)b * NPTS * CCH;
  const float* xxb = xx + (b << 12);

  // query B-frags pinned in registers: qfrag[qt][ks], k = ks*32 + quad*8 + j
  bf16x8 qfrag[2][4];
  #pragma unroll
  for (int qt = 0; qt < 2; qt++) {
    const short* qrow = xb + (size_t)(q0 + qt * 16 + m) * CCH;
    #pragma unroll
    for (int ks = 0; ks < 4; ks++)
      qfrag[qt][ks] = *(const bf16x8*)(qrow + ks * 32 + quad * 8);
  }

  float lv[2][8]; int li[2][8];
  #pragma unroll
  for (int qt = 0; qt < 2; qt++)
    #pragma unroll
    for (int p = 0; p < 8; p++) { lv[qt][p] = -3.4e38f; li[qt][p] = 0x7fffffff; }

  // staging slots (constant): f = tid + i*256 -> row fr, granule fg (16B units)
  int fr[8], fg[8];
  uint4 pf[8];
  #pragma unroll
  for (int i = 0; i < 8; i++) {
    int f = tid + i * 256; fr[i] = f >> 4; fg[i] = f & 15;
    pf[i] = *(const uint4*)(xb + (size_t)fr[i] * CCH + fg[i] * 8);
  }

  const f32x4 zero4 = {0.f, 0.f, 0.f, 0.f};

  for (int c = 0; c < 32; c++) {
    __syncthreads(); // previous chunk's reads complete
    #pragma unroll
    for (int i = 0; i < 8; i++)
      *(uint4*)&Acs[fr[i] * 128 + ((fg[i] ^ (fr[i] & 15)) * 8)] = pf[i];
    if (c < 31) {
      const short* src = xb + (size_t)(c + 1) * 128 * CCH;
      #pragma unroll
      for (int i = 0; i < 8; i++)
        pf[i] = *(const uint4*)(src + (size_t)fr[i] * CCH + fg[i] * 8);
    }
    // xx for this chunk's cand rows (broadcast loads, hidden behind barrier)
    float xv[2][4];
    #pragma unroll
    for (int ct = 0; ct < 2; ct++)
      #pragma unroll
      for (int r = 0; r < 4; r++)
        xv[ct][r] = xxb[c * 128 + wave * 32 + ct * 16 + quad * 4 + r];
    __syncthreads(); // staging visible

    f32x4 acc[2][2];
    #pragma unroll
    for (int ct = 0; ct < 2; ct++)
      #pragma unroll
      for (int qt = 0; qt < 2; qt++) acc[ct][qt] = zero4;

    #pragma unroll
    for (int ks = 0; ks < 4; ks++) {
      bf16x8 af[2];
      #pragma unroll
      for (int ct = 0; ct < 2; ct++) {
        int row = wave * 32 + ct * 16 + m;           // row&15 == m
        int slot = (ks * 4 + quad) ^ m;              // swizzled granule
        af[ct] = *(const bf16x8*)&Acs[row * 128 + slot * 8];
      }
      #pragma unroll
      for (int ct = 0; ct < 2; ct++)
        #pragma unroll
        for (int qt = 0; qt < 2; qt++)
          acc[ct][qt] = __builtin_amdgcn_mfma_f32_16x16x32_bf16(
              af[ct], qfrag[qt][ks], acc[ct][qt], 0, 0, 0);
    }

    // fused selection: key = 2*acc - xx_m; branchy insert (rare after warmup)
    #pragma unroll
    for (int ct = 0; ct < 2; ct++) {
      #pragma unroll
      for (int r = 0; r < 4; r++) {
        int ci = c * 128 + wave * 32 + ct * 16 + quad * 4 + r;
        float nxx = -xv[ct][r];
        #pragma unroll
        for (int qt = 0; qt < 2; qt++) {
          float key = fmaf(2.f, acc[ct][qt][r], nxx);
          if (key > lv[qt][7]) {
            float cv = key; int cidx = ci;
            #pragma unroll
            for (int p = 0; p < 8; p++) {
              bool gt = cv > lv[qt][p];
              float ov = lv[qt][p]; int oi = li[qt][p];
              lv[qt][p] = gt ? cv : ov; li[qt][p] = gt ? cidx : oi;
              cv = gt ? ov : cv;       cidx = gt ? oi : cidx;
            }
          }
        }
      }
    }
  }

  // write per-lane lists: [q][16 lanes][8 entries] (v, idx-as-float)
  int slot = wave * 4 + quad;
  #pragma unroll
  for (int qt = 0; qt < 2; qt++) {
    int q = q0 + qt * 16 + m;
    float2* dst = cand + ((size_t)((b << 12) + q) * 16 + slot) * 8;
    #pragma unroll
    for (int p = 0; p < 8; p++)
      dst[p] = make_float2(lv[qt][p], __int_as_float(li[qt][p]));
  }
}

// ---------------- K2b: merge 128 approx entries -> top-16 -> exact fp32 re-rank -> top-9 ----------------
__launch_bounds__(256)
__global__ void k_rerank(const float2* __restrict__ cand, const float* __restrict__ xt,
                         const float* __restrict__ xx, int* __restrict__ idxOut) {
  __shared__ float2 arr[4][128];
  __shared__ int selS[4][16];
  __shared__ float keyS[4][16];
  int tid = threadIdx.x, wave = tid >> 6, lane = tid & 63;
  int qg = blockIdx.x * 4 + wave;
  int b = qg >> 12;
  const float2* src = cand + (size_t)qg * 128;
  float2 e1 = src[lane], e2 = src[lane + 64];
  arr[wave][lane] = e1; arr[wave][lane + 64] = e2;
  __syncthreads();
  float v1 = e1.x, v2 = e2.x;
  int i1 = __float_as_int(e1.y), i2 = __float_as_int(e2.y);
  int r1 = 0, r2 = 0;
  for (int f = 0; f < 128; f++) {
    float2 fe = arr[wave][f];
    float fv = fe.x; int fi = __float_as_int(fe.y);
    r1 += (fv > v1) || (fv == v1 && fi < i1);
    r2 += (fv > v2) || (fv == v2 && fi < i2);
  }
  if (r1 < 16) selS[wave][r1] = i1;
  if (r2 < 16) selS[wave][r2] = i2;
  __syncthreads();
  // exact fp32 keys for 16 candidates: 4 lanes per candidate, 32 ch each
  int cnum = lane >> 2, part = lane & 3;
  int cidx = selS[wave][cnum];
  const float* rq = xt + (size_t)qg * CCH;
  const float* rc = xt + ((size_t)(b << 12) + cidx) * CCH;
  float dot = 0.f;
  #pragma unroll
  for (int j = 0; j < 8; j++) {
    float4 a4 = *(const float4*)&rq[part * 32 + j * 4];
    float4 c4 = *(const float4*)&rc[part * 32 + j * 4];
    dot += a4.x * c4.x + a4.y * c4.y + a4.z * c4.z + a4.w * c4.w;
  }
  dot += __shfl_xor(dot, 1);
  dot += __shfl_xor(dot, 2);
  if (part == 0)
    keyS[wave][cnum] = fmaf(2.f, dot, -xx[(b << 12) + cidx]);
  __syncthreads();
  if (lane < 16) {
    float k = keyS[wave][lane]; int i = selS[wave][lane];
    int r = 0;
    #pragma unroll
    for (int f = 0; f < 16; f++) {
      float fk = keyS[wave][f]; int fi = selS[wave][f];
      r += (fk > k) || (fk == k && fi < i);
    }
    if (r < 9) idxOut[(size_t)qg * 9 + r] = i;
  }
}

// ---------------- K3: O[pos][0:128]=u=(Wa+Wb)x+b_lin, [128:256]=v=Wb x, [256:292]=aw logits ----------------
__launch_bounds__(256)
__global__ void k_linear(const float* __restrict__ xt, const float* __restrict__ w_lin,
                         const float* __restrict__ b_lin, const float* __restrict__ w_aw,
                         const float* __restrict__ b_aw, float* __restrict__ O) {
  __shared__ __align__(16) float Xs[64 * 132];
  __shared__ __align__(16) float Ws[64 * 132];
  int tid = threadIdx.x;
  int tx = tid & 15, ty = tid >> 4;
  int p0 = blockIdx.x * 64, o0 = blockIdx.y * 64;
  #pragma unroll
  for (int i = 0; i < 8; i++) {
    int flat = tid + i * 256; int r = flat >> 5, c4 = flat & 31;
    *(float4*)&Xs[r * 132 + c4 * 4] = *(const float4*)&xt[(size_t)(p0 + r) * CCH + c4 * 4];
  }
  #pragma unroll
  for (int i = 0; i < 8; i++) {
    int flat = tid + i * 256; int r = flat >> 5, c4 = flat & 31;
    int o = o0 + r; float4 v;
    if (o < 128) {
      float4 a = *(const float4*)&w_lin[(size_t)o * 256 + c4 * 4];
      float4 c = *(const float4*)&w_lin[(size_t)o * 256 + 128 + c4 * 4];
      v = make_float4(a.x + c.x, a.y + c.y, a.z + c.z, a.w + c.w);
    } else if (o < 256) {
      v = *(const float4*)&w_lin[(size_t)(o - 128) * 256 + 128 + c4 * 4];
    } else if (o < 292) {
      v = *(const float4*)&w_aw[(size_t)(o - 256) * 128 + c4 * 4];
    } else v = make_float4(0.f, 0.f, 0.f, 0.f);
    *(float4*)&Ws[r * 132 + c4 * 4] = v;
  }
  __syncthreads();
  float acc[4][4] = {};
  #pragma unroll 2
  for (int kq = 0; kq < 32; kq++) {
    float4 xa[4], wb[4];
    #pragma unroll
    for (int i = 0; i < 4; i++) xa[i] = *(const float4*)&Xs[(ty * 4 + i) * 132 + kq * 4];
    #pragma unroll
    for (int j = 0; j < 4; j++) wb[j] = *(const float4*)&Ws[(tx + 16 * j) * 132 + kq * 4];
    #pragma unroll
    for (int i = 0; i < 4; i++)
      #pragma unroll
      for (int j = 0; j < 4; j++)
        acc[i][j] += xa[i].x * wb[j].x + xa[i].y * wb[j].y + xa[i].z * wb[j].z + xa[i].w * wb[j].w;
  }
  #pragma unroll
  for (int j = 0; j < 4; j++) {
    int o = o0 + tx + 16 * j;
    if (o < 292) {
      float bias = (o < 128) ? b_lin[o] : ((o < 256) ? 0.f : b_aw[o - 256]);
      #pragma unroll
      for (int i = 0; i < 4; i++)
        O[(size_t)(p0 + ty * 4 + i) * 296 + o] = acc[i][j] + bias;
    }
  }
}

// ---------------- K4: per-point grouped attention, residual, GN partials ----------------
__launch_bounds__(256)
__global__ void k_attn(const float* __restrict__ O, const int* __restrict__ idxArr,
                       const float* __restrict__ xt, float* __restrict__ Y,
                       float* __restrict__ gnPart) {
  __shared__ __align__(16) float fF[4][1188];
  __shared__ __align__(16) float fE[4][1188];
  __shared__ __align__(16) float scS[4][432];
  __shared__ float awS[4][48];
  __shared__ float w9S[4][48];
  __shared__ int tI[45], tJ[45];
  int tid = threadIdx.x;
  int wave = tid >> 6, l = tid & 63;
  int pos = blockIdx.x * 4 + wave;
  int b = pos >> 12;
  if (tid == 0) {
    int p = 0;
    for (int i = 0; i < 9; i++) for (int j = i; j < 9; j++) { tI[p] = i; tJ[p] = j; p++; }
  }
  int nbr[9];
  const float* Op = O + (size_t)pos * 296;
  #pragma unroll
  for (int k = 0; k < 9; k++) nbr[k] = idxArr[(size_t)pos * 9 + k];
  float2 u = *(const float2*)(Op + 2 * l);
  float* fFw = fF[wave];
  float* fEw = fE[wave];
  #pragma unroll
  for (int k = 0; k < 9; k++) {
    const float* vp = O + (size_t)((b << 12) + nbr[k]) * 296 + 128;
    float2 vv = *(const float2*)(vp + 2 * l);
    float f0 = u.x - vv.x, f1 = u.y - vv.y;
    fFw[k * 132 + 2 * l]     = f0;
    fFw[k * 132 + 2 * l + 1] = f1;
    fEw[k * 132 + 2 * l]     = f0 > 0.f ? f0 : __expf(f0) - 1.f;
    fEw[k * 132 + 2 * l + 1] = f1 > 0.f ? f1 : __expf(f1) - 1.f;
  }
  __syncthreads();
  #pragma unroll
  for (int r = 0; r < 3; r++) {
    int p = r * 64 + l;
    if (p < 180) {
      int g = p / 45, q = p - g * 45;
      int i = tI[q], j = tJ[q];
      const float* fi = fFw + i * 132 + g * 32;
      const float* fj = fFw + j * 132 + g * 32;
      float s = 0.f;
      #pragma unroll
      for (int t8 = 0; t8 < 8; t8++) {
        float4 a4 = *(const float4*)(fi + 4 * t8);
        float4 b4 = *(const float4*)(fj + 4 * t8);
        s += a4.x * b4.x + a4.y * b4.y + a4.z * b4.z + a4.w * b4.w;
      }
      s *= 0.17677669529663687f; // 1/sqrt(32)
      scS[wave][(g * 9 + i) * 12 + j] = s;
      scS[wave][(g * 9 + j) * 12 + i] = s;
    }
  }
  __syncthreads();
  if (l < 36) {
    int g = l / 9, i = l - g * 9;
    float* rp = &scS[wave][(g * 9 + i) * 12];
    float mx = rp[0];
    #pragma unroll
    for (int j = 1; j < 9; j++) mx = fmaxf(mx, rp[j]);
    float e[9]; float sm = 0.f;
    #pragma unroll
    for (int j = 0; j < 9; j++) { e[j] = __expf(rp[j] - mx); sm += e[j]; }
    float inv = 1.f / sm;
    #pragma unroll
    for (int j = 0; j < 9; j++) rp[j] = e[j] * inv;
  } else if (l < 40) {
    int g = l - 36;
    float a[9]; float mx = -3.4e38f;
    #pragma unroll
    for (int k = 0; k < 9; k++) { a[k] = Op[256 + g * 9 + k]; mx = fmaxf(mx, a[k]); }
    float sm = 0.f;
    #pragma unroll
    for (int k = 0; k < 9; k++) { a[k] = __expf(a[k] - mx); sm += a[k]; }
    float inv = 1.f / sm;
    #pragma unroll
    for (int k = 0; k < 9; k++) awS[wave][g * 12 + k] = a[k] * inv;
  }
  __syncthreads();
  if (l < 36) {
    int g = l / 9, j = l - g * 9;
    float s = 0.f;
    #pragma unroll
    for (int i = 0; i < 9; i++) s += awS[wave][g * 12 + i] * scS[wave][(g * 9 + i) * 12 + j];
    w9S[wave][g * 12 + j] = s;
  }
  __syncthreads();
  int g = l >> 4;
  float w9r[9];
  #pragma unroll
  for (int j = 0; j < 9; j++) w9r[j] = w9S[wave][g * 12 + j];
  int c0 = 2 * l;
  float lf0 = 0.f, lf1 = 0.f;
  #pragma unroll
  for (int j = 0; j < 9; j++) {
    lf0 += w9r[j] * fEw[j * 132 + c0];
    lf1 += w9r[j] * fEw[j * 132 + c0 + 1];
  }
  float2 xv = *(const float2*)(xt + (size_t)pos * CCH + c0);
  float y0 = lf0 + xv.x, y1 = lf1 + xv.y;
  *(float2*)(Y + (size_t)pos * CCH + c0) = make_float2(y0, y1);
  float s1 = y0 + y1, s2 = y0 * y0 + y1 * y1;
  #pragma unroll
  for (int mm = 1; mm <= 8; mm <<= 1) { s1 += __shfl_xor(s1, mm); s2 += __shfl_xor(s2, mm); }
  if ((l & 15) == 0) {
    gnPart[(size_t)pos * 8 + g * 2]     = s1;
    gnPart[(size_t)pos * 8 + g * 2 + 1] = s2;
  }
}

// ---------------- K5: GN stats -> per (b,c) affine a,d ----------------
__global__ void k_gnstats(const float* __restrict__ gnPart,
                          const float* __restrict__ gn_g, const float* __restrict__ gn_b,
                          float* __restrict__ gnA, float* __restrict__ gnD) {
  int bg = blockIdx.x; int b = bg >> 2, g = bg & 3;
  int tid = threadIdx.x;
  float s1 = 0.f, s2 = 0.f;
  for (int r = tid; r < NPTS; r += 256) {
    const float* p = gnPart + (size_t)(b * NPTS + r) * 8 + g * 2;
    s1 += p[0]; s2 += p[1];
  }
  __shared__ float r1[256], r2[256];
  r1[tid] = s1; r2[tid] = s2;
  __syncthreads();
  for (int off = 128; off > 0; off >>= 1) {
    if (tid < off) { r1[tid] += r1[tid + off]; r2[tid] += r2[tid + off]; }
    __syncthreads();
  }
  __shared__ float muS, rsS;
  if (tid == 0) {
    float mu = r1[0] * (1.f / 131072.f);
    float var = r2[0] * (1.f / 131072.f) - mu * mu;
    muS = mu; rsS = 1.f / sqrtf(var + 1e-5f);
  }
  __syncthreads();
  if (tid < 32) {
    int c = g * 32 + tid;
    float a = rsS * gn_g[c];
    gnA[b * 128 + c] = a;
    gnD[b * 128 + c] = gn_b[c] - muS * a;
  }
}

// ---------------- K5b: fold GN affine into conv weights per batch ----------------
__global__ void k_fold(const float* __restrict__ conv_w, const float* __restrict__ conv_b,
                       const float* __restrict__ gnA, const float* __restrict__ gnD,
                       float* __restrict__ Wp, float* __restrict__ biasp) {
  int b = blockIdx.x; int tid = threadIdx.x;
  __shared__ float dS[128], aS[128];
  if (tid < 128) { dS[tid] = gnD[b * 128 + tid]; aS[tid] = gnA[b * 128 + tid]; }
  __syncthreads();
  for (int f = tid; f < 16384; f += 256)
    Wp[(size_t)b * 16384 + f] = conv_w[f] * aS[f & 127];
  if (tid < 128) {
    float s = conv_b[tid];
    for (int c = 0; c < 128; c++) s += conv_w[tid * 128 + c] * dS[c];
    biasp[b * 128 + tid] = s;
  }
}

// ---------------- K6: conv GEMM on raw y + BN partial sums ----------------
__launch_bounds__(256)
__global__ void k_conv(const float* __restrict__ Y, const float* __restrict__ Wp,
                       const float* __restrict__ biasp, float* __restrict__ zpre,
                       float* __restrict__ bnSum, float* __restrict__ bnSq) {
  __shared__ __align__(16) float Ys[64 * 132];
  __shared__ __align__(16) float Ws[64 * 132];
  int tid = threadIdx.x;
  int tx = tid & 15, ty = tid >> 4;
  int n0 = blockIdx.x * 64, o0 = blockIdx.y * 64, b = blockIdx.z;
  #pragma unroll
  for (int i = 0; i < 8; i++) {
    int flat = tid + i * 256; int r = flat >> 5, c4 = flat & 31;
    *(float4*)&Ys[r * 132 + c4 * 4] = *(const float4*)&Y[(size_t)((b << 12) + n0 + r) * CCH + c4 * 4];
    *(float4*)&Ws[r * 132 + c4 * 4] = *(const float4*)&Wp[(size_t)b * 16384 + (size_t)(o0 + r) * 128 + c4 * 4];
  }
  __syncthreads();
  float acc[4][4] = {};
  #pragma unroll 2
  for (int kq = 0; kq < 32; kq++) {
    float4 wa[4], yb[4];
    #pragma unroll
    for (int i = 0; i < 4; i++) wa[i] = *(const float4*)&Ws[(ty * 4 + i) * 132 + kq * 4];
    #pragma unroll
    for (int j = 0; j < 4; j++) yb[j] = *(const float4*)&Ys[(tx + 16 * j) * 132 + kq * 4];
    #pragma unroll
    for (int i = 0; i < 4; i++)
      #pragma unroll
      for (int j = 0; j < 4; j++)
        acc[i][j] += wa[i].x * yb[j].x + wa[i].y * yb[j].y + wa[i].z * yb[j].z + wa[i].w * yb[j].w;
  }
  #pragma unroll
  for (int i = 0; i < 4; i++) {
    int o = o0 + ty * 4 + i;
    float bias = biasp[b * 128 + o];
    float p1 = 0.f, p2 = 0.f;
    #pragma unroll
    for (int j = 0; j < 4; j++) {
      float z = acc[i][j] + bias;
      zpre[(((size_t)((b << 7) + o)) << 12) + n0 + tx + 16 * j] = z;
      p1 += z; p2 += z * z;
    }
    #pragma unroll
    for (int mm = 1; mm <= 8; mm <<= 1) { p1 += __shfl_xor(p1, mm); p2 += __shfl_xor(p2, mm); }
    if (tx == 0) { atomicAdd(&bnSum[o], p1); atomicAdd(&bnSq[o], p2); }
  }
}

// ---------------- K7a: BN finalize ----------------
__global__ void k_bnfin(const float* __restrict__ bnSum, const float* __restrict__ bnSq,
                        const float* __restrict__ bn_g, const float* __restrict__ bn_b,
                        float* __restrict__ bnScale, float* __restrict__ bnShift) {
  int o = threadIdx.x;
  float m = bnSum[o] * (1.f / 16384.f);
  float v = bnSq[o] * (1.f / 16384.f) - m * m;
  float sc = bn_g[o] / sqrtf(v + 1e-5f);
  bnScale[o] = sc;
  bnShift[o] = bn_b[o] - m * sc;
}

// ---------------- K7b: normalize + ReLU -> d_out ----------------
__global__ void k_final(const float* __restrict__ zpre, const float* __restrict__ bnScale,
                        const float* __restrict__ bnShift, float* __restrict__ out) {
  int i4 = blockIdx.x * 256 + threadIdx.x;
  int e = i4 * 4;
  int o = (e >> 12) & 127;
  float4 z = *(const float4*)&zpre[e];
  float sc = bnScale[o], sh = bnShift[o];
  float4 r;
  r.x = fmaxf(fmaf(z.x, sc, sh), 0.f);
  r.y = fmaxf(fmaf(z.y, sc, sh), 0.f);
  r.z = fmaxf(fmaf(z.z, sc, sh), 0.f);
  r.w = fmaxf(fmaf(z.w, sc, sh), 0.f);
  *(float4*)&out[e] = r;
}

extern "C" void kernel_launch(void* const* d_in, const int* in_sizes, int n_in,
                              void* d_out, int out_size, void* d_ws, size_t ws_size,
                              hipStream_t stream) {
  const float* features = (const float*)d_in[0];
  const float* w_lin  = (const float*)d_in[1];
  const float* b_lin  = (const float*)d_in[2];
  const float* w_aw   = (const float*)d_in[3];
  const float* b_aw   = (const float*)d_in[4];
  const float* gn_g   = (const float*)d_in[5];
  const float* gn_b   = (const float*)d_in[6];
  const float* conv_w = (const float*)d_in[7];
  const float* conv_b = (const float*)d_in[8];
  const float* bn_g   = (const float*)d_in[9];
  const float* bn_b   = (const float*)d_in[10];

  float* ws    = (float*)d_ws;
  float* xt    = ws + OFF_XT;
  float* xxp   = ws + OFF_XX;
  __hip_bfloat16* xhip = (__hip_bfloat16*)(ws + OFF_XHI);
  int*   idxp  = (int*)(ws + OFF_IDX);
  float* Op    = ws + OFF_O;
  float2* candp = (float2*)(ws + OFF_O);   // alias: dead before k_linear writes O
  float* Yp    = ws + OFF_Y;
  float* gnp   = ws + OFF_GNP;
  float* gnA   = ws + OFF_GNA;
  float* gnD   = ws + OFF_GND;
  float* Wp    = ws + OFF_WP;
  float* biasp = ws + OFF_BIASP;
  float* bnSum = ws + OFF_BNSUM;
  float* bnSq  = ws + OFF_BNSQ;
  float* bnSc  = ws + OFF_BNSC;
  float* bnSh  = ws + OFF_BNSH;
  float* zpre  = xt; // alias: xt dead after k_attn

  hipMemsetAsync(xxp, 0, NPTS * BB * sizeof(float), stream);
  hipMemsetAsync(bnSum, 0, 256 * sizeof(float), stream); // bnSum + bnSq contiguous

  k_transpose<<<dim3(128, 4, 4), dim3(32, 32), 0, stream>>>(features, xt, xhip, xxp);
  k_knn<<<dim3(128, 4), 256, 0, stream>>>((const short*)xhip, xxp, candp);
  k_rerank<<<4096, 256, 0, stream>>>(candp, xt, xxp, idxp);
  k_linear<<<dim3(256, 5), 256, 0, stream>>>(xt, w_lin, b_lin, w_aw, b_aw, Op);
  k_attn<<<4096, 256, 0, stream>>>(Op, idxp, xt, Yp, gnp);
  k_gnstats<<<16, 256, 0, stream>>>(gnp, gn_g, gn_b, gnA, gnD);
  k_fold<<<4, 256, 0, stream>>>(conv_w, conv_b, gnA, gnD, Wp, biasp);
  k_conv<<<dim3(64, 2, 4), 256, 0, stream>>>(Yp, Wp, biasp, zpre, bnSum, bnSq);
  k_bnfin<<<1, 128, 0, stream>>>(bnSum, bnSq, bn_g, bn_b, bnSc, bnSh);
  k_final<<<2048, 256, 0, stream>>>(zpre, bnSc, bnSh, (float*)d_out);
}

// Round 5
// 314.318 us; speedup vs baseline: 3.4287x; 1.4678x over previous
//
#include <hip/hip_runtime.h>
#include <hip/hip_bf16.h>
#include <cstddef>

// Problem constants
#define NPTS 4096
#define CCH  128
#define KNN  9
#define GRP  4
#define BB   4
// workspace layout (float offsets)
#define OFF_XT    0u          // 2097152 floats (reused as zpre after k_attn)
#define OFF_XX    2097152u    // 16384
#define OFF_XHI   2113536u    // 1048576 float-slots = 2097152 bf16 (pre-swizzled)
#define OFF_IDX   3162112u    // 147456 ints
#define OFF_O     3309568u    // 4849664 (candbuf aliases first 2097152 floats)
#define OFF_Y     8159232u    // 2097152
#define OFF_GNP   10256384u   // 131072
#define OFF_GNA   10387456u   // 512
#define OFF_GND   10387968u   // 512
#define OFF_WP    10388480u   // 65536
#define OFF_BIASP 10454016u   // 512
#define OFF_BNSUM 10454528u   // 128
#define OFF_BNSQ  10454656u   // 128
#define OFF_BNSC  10454784u   // 128
#define OFF_BNSH  10454912u   // 128

using bf16x8 = __attribute__((ext_vector_type(8))) short;
using f32x4  = __attribute__((ext_vector_type(4))) float;

typedef __attribute__((address_space(1))) const unsigned as1c_u32;
typedef __attribute__((address_space(3))) unsigned as3_u32;

// Packed sentinel: monotone-map(-FLT_MAX) truncated to 20 key bits, idx=0.
// Reverse map gives -3.4028e38 (valid float, NOT NaN) so thr stays sane.
#define TOP8_INIT 0x00800000u

// ---------------- K1: transpose [B,C,N] -> xt [B*N,C] fp32 + pre-swizzled bf16 xhi + xx ----
// xhi swizzle: 16B granule g (8 bf16) of row R stored at slot g ^ (R&15), so a LINEAR
// global->LDS DMA of a 128-row chunk reproduces the conflict-free swizzled LDS layout.
__global__ void k_transpose(const float* __restrict__ x, float* __restrict__ xt,
                            __hip_bfloat16* __restrict__ xhi, float* __restrict__ xx) {
  __shared__ float t[32][33];
  int tx = threadIdx.x, ty = threadIdx.y;
  int n0 = blockIdx.x * 32, c0 = blockIdx.y * 32, b = blockIdx.z;
  float v = x[((size_t)b * CCH + c0 + ty) * NPTS + n0 + tx];
  t[ty][tx] = v;
  __syncthreads();
  float tv = t[tx][ty];
  size_t R = (size_t)b * NPTS + n0 + ty;
  int c = c0 + tx;
  xt[R * CCH + c] = tv;
  int g = c >> 3, w = c & 7;
  int sc = (((g ^ ((n0 + ty) & 15)) << 3) | w);
  xhi[R * CCH + sc] = __float2bfloat16(tv);
  if (ty == 0) {
    float s = 0.f;
    #pragma unroll
    for (int k = 0; k < 32; k++) { float u = t[k][tx]; s += u * u; }
    atomicAdd(&xx[b * NPTS + n0 + tx], s);
  }
}

// ---------------- K2: MFMA Gram (bf16) + fused per-lane packed top-8 ----------------
// 256 thr = 4 waves, 32 queries/block (q-frags in regs), 128-cand chunks.
// Staging: async global_load_lds (width 16) into double-buffered LDS; global xhi is
// pre-swizzled so the linear DMA lands in the verified conflict-free layout.
// Selection state: packed uint = 20 key bits (monotone-mapped fp32) | 12 idx bits.
__launch_bounds__(256, 2)
__global__ void k_knn(const short* __restrict__ xhi, const float* __restrict__ xx,
                      unsigned* __restrict__ cand) {
  __shared__ short Acs[2][16384]; // 2 x 32 KB
  const int tid = threadIdx.x;
  const int wave = tid >> 6, lane = tid & 63;
  const int quad = lane >> 4, m = lane & 15;
  const int b = blockIdx.y;
  const int q0 = blockIdx.x * 32;
  const short* xb = xhi + (size_t)b * NPTS * CCH;
  const float* xxb = xx + (b << 12);

  const char* gsrc0 = (const char*)xb + wave * 8192 + lane * 16;

  // prologue: stage chunk 0 into buffer 0
  #pragma unroll
  for (int i = 0; i < 8; i++)
    __builtin_amdgcn_global_load_lds((as1c_u32*)(gsrc0 + i * 1024),
                                     (as3_u32*)&Acs[0][wave * 4096 + i * 512],
                                     16, 0, 0);

  // query B-frags (un-swizzle: granule ks*4+quad at slot ^(row&15), row&15==m)
  bf16x8 qfrag[2][4];
  #pragma unroll
  for (int qt = 0; qt < 2; qt++) {
    const short* qrow = xb + (size_t)(q0 + qt * 16 + m) * CCH;
    #pragma unroll
    for (int ks = 0; ks < 4; ks++) {
      int slot = (ks * 4 + quad) ^ m;
      qfrag[qt][ks] = *(const bf16x8*)(qrow + slot * 8);
    }
  }

  unsigned top8[2][8];
  float thr[2] = {-3.4e38f, -3.4e38f};
  #pragma unroll
  for (int qt = 0; qt < 2; qt++)
    #pragma unroll
    for (int p = 0; p < 8; p++) top8[qt][p] = TOP8_INIT; // BUGFIX: was 0u -> thr became NaN

  const f32x4 zero4 = {0.f, 0.f, 0.f, 0.f};

  for (int c = 0; c < 32; c++) {
    __syncthreads(); // drains chunk-c DMA (and prior ds_reads)
    if (c < 31) {
      const char* gsrc = gsrc0 + (size_t)(c + 1) * 32768;
      int bi = (c + 1) & 1;
      #pragma unroll
      for (int i = 0; i < 8; i++)
        __builtin_amdgcn_global_load_lds((as1c_u32*)(gsrc + i * 1024),
                                         (as3_u32*)&Acs[bi][wave * 4096 + i * 512],
                                         16, 0, 0);
    }
    float xv[2][4];
    #pragma unroll
    for (int ct = 0; ct < 2; ct++)
      #pragma unroll
      for (int r = 0; r < 4; r++)
        xv[ct][r] = xxb[c * 128 + wave * 32 + ct * 16 + quad * 4 + r];

    const short* cur = &Acs[c & 1][0];
    f32x4 acc[2][2];
    #pragma unroll
    for (int ct = 0; ct < 2; ct++)
      #pragma unroll
      for (int qt = 0; qt < 2; qt++) acc[ct][qt] = zero4;

    #pragma unroll
    for (int ks = 0; ks < 4; ks++) {
      bf16x8 af[2];
      #pragma unroll
      for (int ct = 0; ct < 2; ct++) {
        int row = wave * 32 + ct * 16 + m;
        int slot = (ks * 4 + quad) ^ m;
        af[ct] = *(const bf16x8*)&cur[row * 128 + slot * 8];
      }
      #pragma unroll
      for (int ct = 0; ct < 2; ct++)
        #pragma unroll
        for (int qt = 0; qt < 2; qt++)
          acc[ct][qt] = __builtin_amdgcn_mfma_f32_16x16x32_bf16(
              af[ct], qfrag[qt][ks], acc[ct][qt], 0, 0, 0);
    }

    // selection: key = 2*acc - xx_m; common path = 1 fma + 1 cmp
    #pragma unroll
    for (int ct = 0; ct < 2; ct++) {
      #pragma unroll
      for (int r = 0; r < 4; r++) {
        int ci = c * 128 + wave * 32 + ct * 16 + quad * 4 + r;
        float nxx = -xv[ct][r];
        #pragma unroll
        for (int qt = 0; qt < 2; qt++) {
          float key = fmaf(2.f, acc[ct][qt][r], nxx);
          if (key > thr[qt]) {
            unsigned u = __float_as_uint(key);
            u ^= ((unsigned)((int)u >> 31)) | 0x80000000u;
            unsigned cv = (u & 0xFFFFF000u) | (unsigned)ci;
            #pragma unroll
            for (int p = 0; p < 8; p++) {
              unsigned ov = top8[qt][p];
              bool gt = cv > ov;
              top8[qt][p] = gt ? cv : ov;
              cv = gt ? ov : cv;
            }
            unsigned mu = top8[qt][7] & 0xFFFFF000u;
            unsigned uu = ((int)mu < 0) ? (mu ^ 0x80000000u) : ~mu;
            thr[qt] = __uint_as_float(uu); // safe lower bound on 8th-best (never NaN now)
          }
        }
      }
    }
  }

  int slot = wave * 4 + quad;
  #pragma unroll
  for (int qt = 0; qt < 2; qt++) {
    int q = q0 + qt * 16 + m;
    unsigned* dst = cand + ((size_t)((b << 12) + q) * 16 + slot) * 8;
    #pragma unroll
    for (int p = 0; p < 8; p++) dst[p] = top8[qt][p];
  }
}

// ---------------- K2b: merge 128 packed -> top-16 -> exact fp32 re-rank -> top-9 --------
__launch_bounds__(256)
__global__ void k_rerank(const unsigned* __restrict__ cand, const float* __restrict__ xt,
                         const float* __restrict__ xx, int* __restrict__ idxOut) {
  __shared__ unsigned arr[4][128];
  __shared__ int selS[4][16];
  __shared__ float keyS[4][16];
  int tid = threadIdx.x, wave = tid >> 6, lane = tid & 63;
  int qg = blockIdx.x * 4 + wave;
  int b = qg >> 12;
  const unsigned* src = cand + (size_t)qg * 128;
  unsigned e1 = src[lane], e2 = src[lane + 64];
  arr[wave][lane] = e1; arr[wave][lane + 64] = e2;
  __syncthreads();
  int r1 = 0, r2 = 0;
  for (int f = 0; f < 128; f++) {
    unsigned fv = arr[wave][f];
    r1 += fv > e1;
    r2 += fv > e2;
  }
  if (r1 < 16) selS[wave][r1] = (int)(e1 & 0xFFFu);
  if (r2 < 16) selS[wave][r2] = (int)(e2 & 0xFFFu);
  __syncthreads();
  // exact fp32 keys: 4 lanes per candidate, 32 channels each
  int cnum = lane >> 2, part = lane & 3;
  int cidx = selS[wave][cnum];
  const float* rq = xt + (size_t)qg * CCH;
  const float* rc = xt + ((size_t)(b << 12) + cidx) * CCH;
  float dot = 0.f;
  #pragma unroll
  for (int j = 0; j < 8; j++) {
    float4 a4 = *(const float4*)&rq[part * 32 + j * 4];
    float4 c4 = *(const float4*)&rc[part * 32 + j * 4];
    dot += a4.x * c4.x + a4.y * c4.y + a4.z * c4.z + a4.w * c4.w;
  }
  dot += __shfl_xor(dot, 1);
  dot += __shfl_xor(dot, 2);
  if (part == 0)
    keyS[wave][cnum] = fmaf(2.f, dot, -xx[(b << 12) + cidx]);
  __syncthreads();
  if (lane < 16) {
    float k = keyS[wave][lane]; int i = selS[wave][lane];
    int r = 0;
    #pragma unroll
    for (int f = 0; f < 16; f++) {
      float fk = keyS[wave][f]; int fi = selS[wave][f];
      r += (fk > k) || (fk == k && fi < i);
    }
    if (r < 9) idxOut[(size_t)qg * 9 + r] = i;
  }
}

// ---------------- K3: O[pos][0:128]=u=(Wa+Wb)x+b_lin, [128:256]=v=Wb x, [256:292]=aw ----
__launch_bounds__(256)
__global__ void k_linear(const float* __restrict__ xt, const float* __restrict__ w_lin,
                         const float* __restrict__ b_lin, const float* __restrict__ w_aw,
                         const float* __restrict__ b_aw, float* __restrict__ O) {
  __shared__ __align__(16) float Xs[64 * 132];
  __shared__ __align__(16) float Ws[64 * 132];
  int tid = threadIdx.x;
  int tx = tid & 15, ty = tid >> 4;
  int p0 = blockIdx.x * 64, o0 = blockIdx.y * 64;
  #pragma unroll
  for (int i = 0; i < 8; i++) {
    int flat = tid + i * 256; int r = flat >> 5, c4 = flat & 31;
    *(float4*)&Xs[r * 132 + c4 * 4] = *(const float4*)&xt[(size_t)(p0 + r) * CCH + c4 * 4];
  }
  #pragma unroll
  for (int i = 0; i < 8; i++) {
    int flat = tid + i * 256; int r = flat >> 5, c4 = flat & 31;
    int o = o0 + r; float4 v;
    if (o < 128) {
      float4 a = *(const float4*)&w_lin[(size_t)o * 256 + c4 * 4];
      float4 c = *(const float4*)&w_lin[(size_t)o * 256 + 128 + c4 * 4];
      v = make_float4(a.x + c.x, a.y + c.y, a.z + c.z, a.w + c.w);
    } else if (o < 256) {
      v = *(const float4*)&w_lin[(size_t)(o - 128) * 256 + 128 + c4 * 4];
    } else if (o < 292) {
      v = *(const float4*)&w_aw[(size_t)(o - 256) * 128 + c4 * 4];
    } else v = make_float4(0.f, 0.f, 0.f, 0.f);
    *(float4*)&Ws[r * 132 + c4 * 4] = v;
  }
  __syncthreads();
  float acc[4][4] = {};
  #pragma unroll 2
  for (int kq = 0; kq < 32; kq++) {
    float4 xa[4], wb[4];
    #pragma unroll
    for (int i = 0; i < 4; i++) xa[i] = *(const float4*)&Xs[(ty * 4 + i) * 132 + kq * 4];
    #pragma unroll
    for (int j = 0; j < 4; j++) wb[j] = *(const float4*)&Ws[(tx + 16 * j) * 132 + kq * 4];
    #pragma unroll
    for (int i = 0; i < 4; i++)
      #pragma unroll
      for (int j = 0; j < 4; j++)
        acc[i][j] += xa[i].x * wb[j].x + xa[i].y * wb[j].y + xa[i].z * wb[j].z + xa[i].w * wb[j].w;
  }
  #pragma unroll
  for (int j = 0; j < 4; j++) {
    int o = o0 + tx + 16 * j;
    if (o < 292) {
      float bias = (o < 128) ? b_lin[o] : ((o < 256) ? 0.f : b_aw[o - 256]);
      #pragma unroll
      for (int i = 0; i < 4; i++)
        O[(size_t)(p0 + ty * 4 + i) * 296 + o] = acc[i][j] + bias;
    }
  }
}

// ---------------- K4: per-point grouped attention, residual, GN partials ----------------
__launch_bounds__(256)
__global__ void k_attn(const float* __restrict__ O, const int* __restrict__ idxArr,
                       const float* __restrict__ xt, float* __restrict__ Y,
                       float* __restrict__ gnPart) {
  __shared__ __align__(16) float fF[4][1188];
  __shared__ __align__(16) float fE[4][1188];
  __shared__ __align__(16) float scS[4][432];
  __shared__ float awS[4][48];
  __shared__ float w9S[4][48];
  __shared__ int tI[45], tJ[45];
  int tid = threadIdx.x;
  int wave = tid >> 6, l = tid & 63;
  int pos = blockIdx.x * 4 + wave;
  int b = pos >> 12;
  if (tid == 0) {
    int p = 0;
    for (int i = 0; i < 9; i++) for (int j = i; j < 9; j++) { tI[p] = i; tJ[p] = j; p++; }
  }
  int nbr[9];
  const float* Op = O + (size_t)pos * 296;
  #pragma unroll
  for (int k = 0; k < 9; k++) nbr[k] = idxArr[(size_t)pos * 9 + k];
  float2 u = *(const float2*)(Op + 2 * l);
  float* fFw = fF[wave];
  float* fEw = fE[wave];
  #pragma unroll
  for (int k = 0; k < 9; k++) {
    const float* vp = O + (size_t)((b << 12) + nbr[k]) * 296 + 128;
    float2 vv = *(const float2*)(vp + 2 * l);
    float f0 = u.x - vv.x, f1 = u.y - vv.y;
    fFw[k * 132 + 2 * l]     = f0;
    fFw[k * 132 + 2 * l + 1] = f1;
    fEw[k * 132 + 2 * l]     = f0 > 0.f ? f0 : __expf(f0) - 1.f;
    fEw[k * 132 + 2 * l + 1] = f1 > 0.f ? f1 : __expf(f1) - 1.f;
  }
  __syncthreads();
  #pragma unroll
  for (int r = 0; r < 3; r++) {
    int p = r * 64 + l;
    if (p < 180) {
      int g = p / 45, q = p - g * 45;
      int i = tI[q], j = tJ[q];
      const float* fi = fFw + i * 132 + g * 32;
      const float* fj = fFw + j * 132 + g * 32;
      float s = 0.f;
      #pragma unroll
      for (int t8 = 0; t8 < 8; t8++) {
        float4 a4 = *(const float4*)(fi + 4 * t8);
        float4 b4 = *(const float4*)(fj + 4 * t8);
        s += a4.x * b4.x + a4.y * b4.y + a4.z * b4.z + a4.w * b4.w;
      }
      s *= 0.17677669529663687f; // 1/sqrt(32)
      scS[wave][(g * 9 + i) * 12 + j] = s;
      scS[wave][(g * 9 + j) * 12 + i] = s;
    }
  }
  __syncthreads();
  if (l < 36) {
    int g = l / 9, i = l - g * 9;
    float* rp = &scS[wave][(g * 9 + i) * 12];
    float mx = rp[0];
    #pragma unroll
    for (int j = 1; j < 9; j++) mx = fmaxf(mx, rp[j]);
    float e[9]; float sm = 0.f;
    #pragma unroll
    for (int j = 0; j < 9; j++) { e[j] = __expf(rp[j] - mx); sm += e[j]; }
    float inv = 1.f / sm;
    #pragma unroll
    for (int j = 0; j < 9; j++) rp[j] = e[j] * inv;
  } else if (l < 40) {
    int g = l - 36;
    float a[9]; float mx = -3.4e38f;
    #pragma unroll
    for (int k = 0; k < 9; k++) { a[k] = Op[256 + g * 9 + k]; mx = fmaxf(mx, a[k]); }
    float sm = 0.f;
    #pragma unroll
    for (int k = 0; k < 9; k++) { a[k] = __expf(a[k] - mx); sm += a[k]; }
    float inv = 1.f / sm;
    #pragma unroll
    for (int k = 0; k < 9; k++) awS[wave][g * 12 + k] = a[k] * inv;
  }
  __syncthreads();
  if (l < 36) {
    int g = l / 9, j = l - g * 9;
    float s = 0.f;
    #pragma unroll
    for (int i = 0; i < 9; i++) s += awS[wave][g * 12 + i] * scS[wave][(g * 9 + i) * 12 + j];
    w9S[wave][g * 12 + j] = s;
  }
  __syncthreads();
  int g = l >> 4;
  float w9r[9];
  #pragma unroll
  for (int j = 0; j < 9; j++) w9r[j] = w9S[wave][g * 12 + j];
  int c0 = 2 * l;
  float lf0 = 0.f, lf1 = 0.f;
  #pragma unroll
  for (int j = 0; j < 9; j++) {
    lf0 += w9r[j] * fEw[j * 132 + c0];
    lf1 += w9r[j] * fEw[j * 132 + c0 + 1];
  }
  float2 xv = *(const float2*)(xt + (size_t)pos * CCH + c0);
  float y0 = lf0 + xv.x, y1 = lf1 + xv.y;
  *(float2*)(Y + (size_t)pos * CCH + c0) = make_float2(y0, y1);
  float s1 = y0 + y1, s2 = y0 * y0 + y1 * y1;
  #pragma unroll
  for (int mm = 1; mm <= 8; mm <<= 1) { s1 += __shfl_xor(s1, mm); s2 += __shfl_xor(s2, mm); }
  if ((l & 15) == 0) {
    gnPart[(size_t)pos * 8 + g * 2]     = s1;
    gnPart[(size_t)pos * 8 + g * 2 + 1] = s2;
  }
}

// ---------------- K5: GN stats -> per (b,c) affine a,d ----------------
__global__ void k_gnstats(const float* __restrict__ gnPart,
                          const float* __restrict__ gn_g, const float* __restrict__ gn_b,
                          float* __restrict__ gnA, float* __restrict__ gnD) {
  int bg = blockIdx.x; int b = bg >> 2, g = bg & 3;
  int tid = threadIdx.x;
  float s1 = 0.f, s2 = 0.f;
  for (int r = tid; r < NPTS; r += 256) {
    const float* p = gnPart + (size_t)(b * NPTS + r) * 8 + g * 2;
    s1 += p[0]; s2 += p[1];
  }
  __shared__ float r1[256], r2[256];
  r1[tid] = s1; r2[tid] = s2;
  __syncthreads();
  for (int off = 128; off > 0; off >>= 1) {
    if (tid < off) { r1[tid] += r1[tid + off]; r2[tid] += r2[tid + off]; }
    __syncthreads();
  }
  __shared__ float muS, rsS;
  if (tid == 0) {
    float mu = r1[0] * (1.f / 131072.f);
    float var = r2[0] * (1.f / 131072.f) - mu * mu;
    muS = mu; rsS = 1.f / sqrtf(var + 1e-5f);
  }
  __syncthreads();
  if (tid < 32) {
    int c = g * 32 + tid;
    float a = rsS * gn_g[c];
    gnA[b * 128 + c] = a;
    gnD[b * 128 + c] = gn_b[c] - muS * a;
  }
}

// ---------------- K5b: fold GN affine into conv weights per batch ----------------
__global__ void k_fold(const float* __restrict__ conv_w, const float* __restrict__ conv_b,
                       const float* __restrict__ gnA, const float* __restrict__ gnD,
                       float* __restrict__ Wp, float* __restrict__ biasp) {
  int b = blockIdx.x; int tid = threadIdx.x;
  __shared__ float dS[128], aS[128];
  if (tid < 128) { dS[tid] = gnD[b * 128 + tid]; aS[tid] = gnA[b * 128 + tid]; }
  __syncthreads();
  for (int f = tid; f < 16384; f += 256)
    Wp[(size_t)b * 16384 + f] = conv_w[f] * aS[f & 127];
  if (tid < 128) {
    float s = conv_b[tid];
    for (int c = 0; c < 128; c++) s += conv_w[tid * 128 + c] * dS[c];
    biasp[b * 128 + tid] = s;
  }
}

// ---------------- K6: conv GEMM on raw y + BN partial sums ----------------
__launch_bounds__(256)
__global__ void k_conv(const float* __restrict__ Y, const float* __restrict__ Wp,
                       const float* __restrict__ biasp, float* __restrict__ zpre,
                       float* __restrict__ bnSum, float* __restrict__ bnSq) {
  __shared__ __align__(16) float Ys[64 * 132];
  __shared__ __align__(16) float Ws[64 * 132];
  int tid = threadIdx.x;
  int tx = tid & 15, ty = tid >> 4;
  int n0 = blockIdx.x * 64, o0 = blockIdx.y * 64, b = blockIdx.z;
  #pragma unroll
  for (int i = 0; i < 8; i++) {
    int flat = tid + i * 256; int r = flat >> 5, c4 = flat & 31;
    *(float4*)&Ys[r * 132 + c4 * 4] = *(const float4*)&Y[(size_t)((b << 12) + n0 + r) * CCH + c4 * 4];
    *(float4*)&Ws[r * 132 + c4 * 4] = *(const float4*)&Wp[(size_t)b * 16384 + (size_t)(o0 + r) * 128 + c4 * 4];
  }
  __syncthreads();
  float acc[4][4] = {};
  #pragma unroll 2
  for (int kq = 0; kq < 32; kq++) {
    float4 wa[4], yb[4];
    #pragma unroll
    for (int i = 0; i < 4; i++) wa[i] = *(const float4*)&Ws[(ty * 4 + i) * 132 + kq * 4];
    #pragma unroll
    for (int j = 0; j < 4; j++) yb[j] = *(const float4*)&Ys[(tx + 16 * j) * 132 + kq * 4];
    #pragma unroll
    for (int i = 0; i < 4; i++)
      #pragma unroll
      for (int j = 0; j < 4; j++)
        acc[i][j] += wa[i].x * yb[j].x + wa[i].y * yb[j].y + wa[i].z * yb[j].z + wa[i].w * yb[j].w;
  }
  #pragma unroll
  for (int i = 0; i < 4; i++) {
    int o = o0 + ty * 4 + i;
    float bias = biasp[b * 128 + o];
    float p1 = 0.f, p2 = 0.f;
    #pragma unroll
    for (int j = 0; j < 4; j++) {
      float z = acc[i][j] + bias;
      zpre[(((size_t)((b << 7) + o)) << 12) + n0 + tx + 16 * j] = z;
      p1 += z; p2 += z * z;
    }
    #pragma unroll
    for (int mm = 1; mm <= 8; mm <<= 1) { p1 += __shfl_xor(p1, mm); p2 += __shfl_xor(p2, mm); }
    if (tx == 0) { atomicAdd(&bnSum[o], p1); atomicAdd(&bnSq[o], p2); }
  }
}

// ---------------- K7a: BN finalize ----------------
__global__ void k_bnfin(const float* __restrict__ bnSum, const float* __restrict__ bnSq,
                        const float* __restrict__ bn_g, const float* __restrict__ bn_b,
                        float* __restrict__ bnScale, float* __restrict__ bnShift) {
  int o = threadIdx.x;
  float m = bnSum[o] * (1.f / 16384.f);
  float v = bnSq[o] * (1.f / 16384.f) - m * m;
  float sc = bn_g[o] / sqrtf(v + 1e-5f);
  bnScale[o] = sc;
  bnShift[o] = bn_b[o] - m * sc;
}

// ---------------- K7b: normalize + ReLU -> d_out ----------------
__global__ void k_final(const float* __restrict__ zpre, const float* __restrict__ bnScale,
                        const float* __restrict__ bnShift, float* __restrict__ out) {
  int i4 = blockIdx.x * 256 + threadIdx.x;
  int e = i4 * 4;
  int o = (e >> 12) & 127;
  float4 z = *(const float4*)&zpre[e];
  float sc = bnScale[o], sh = bnShift[o];
  float4 r;
  r.x = fmaxf(fmaf(z.x, sc, sh), 0.f);
  r.y = fmaxf(fmaf(z.y, sc, sh), 0.f);
  r.z = fmaxf(fmaf(z.z, sc, sh), 0.f);
  r.w = fmaxf(fmaf(z.w, sc, sh), 0.f);
  *(float4*)&out[e] = r;
}

extern "C" void kernel_launch(void* const* d_in, const int* in_sizes, int n_in,
                              void* d_out, int out_size, void* d_ws, size_t ws_size,
                              hipStream_t stream) {
  const float* features = (const float*)d_in[0];
  const float* w_lin  = (const float*)d_in[1];
  const float* b_lin  = (const float*)d_in[2];
  const float* w_aw   = (const float*)d_in[3];
  const float* b_aw   = (const float*)d_in[4];
  const float* gn_g   = (const float*)d_in[5];
  const float* gn_b   = (const float*)d_in[6];
  const float* conv_w = (const float*)d_in[7];
  const float* conv_b = (const float*)d_in[8];
  const float* bn_g   = (const float*)d_in[9];
  const float* bn_b   = (const float*)d_in[10];

  float* ws    = (float*)d_ws;
  float* xt    = ws + OFF_XT;
  float* xxp   = ws + OFF_XX;
  __hip_bfloat16* xhip = (__hip_bfloat16*)(ws + OFF_XHI);
  int*   idxp  = (int*)(ws + OFF_IDX);
  float* Op    = ws + OFF_O;
  unsigned* candp = (unsigned*)(ws + OFF_O);   // alias: dead before k_linear writes O
  float* Yp    = ws + OFF_Y;
  float* gnp   = ws + OFF_GNP;
  float* gnA   = ws + OFF_GNA;
  float* gnD   = ws + OFF_GND;
  float* Wp    = ws + OFF_WP;
  float* biasp = ws + OFF_BIASP;
  float* bnSum = ws + OFF_BNSUM;
  float* bnSq  = ws + OFF_BNSQ;
  float* bnSc  = ws + OFF_BNSC;
  float* bnSh  = ws + OFF_BNSH;
  float* zpre  = xt; // alias: xt dead after k_attn

  hipMemsetAsync(xxp, 0, NPTS * BB * sizeof(float), stream);
  hipMemsetAsync(bnSum, 0, 256 * sizeof(float), stream); // bnSum + bnSq contiguous

  k_transpose<<<dim3(128, 4, 4), dim3(32, 32), 0, stream>>>(features, xt, xhip, xxp);
  k_knn<<<dim3(128, 4), 256, 0, stream>>>((const short*)xhip, xxp, candp);
  k_rerank<<<4096, 256, 0, stream>>>(candp, xt, xxp, idxp);
  k_linear<<<dim3(256, 5), 256, 0, stream>>>(xt, w_lin, b_lin, w_aw, b_aw, Op);
  k_attn<<<4096, 256, 0, stream>>>(Op, idxp, xt, Yp, gnp);
  k_gnstats<<<16, 256, 0, stream>>>(gnp, gn_g, gn_b, gnA, gnD);
  k_fold<<<4, 256, 0, stream>>>(conv_w, conv_b, gnA, gnD, Wp, biasp);
  k_conv<<<dim3(64, 2, 4), 256, 0, stream>>>(Yp, Wp, biasp, zpre, bnSum, bnSq);
  k_bnfin<<<1, 128, 0, stream>>>(bnSum, bnSq, bn_g, bn_b, bnSc, bnSh);
  k_final<<<2048, 256, 0, stream>>>(zpre, bnSc, bnSh, (float*)d_out);
}

// Round 7
// 297.371 us; speedup vs baseline: 3.6241x; 1.0570x over previous
//
#include <hip/hip_runtime.h>
#include <hip/hip_bf16.h>
#include <cstddef>

// Problem constants
#define NPTS 4096
#define CCH  128
#define KNN  9
#define GRP  4
#define BB   4
// workspace layout (float offsets)
#define OFF_XT    0u          // 2097152 floats (reused as zpre after k_attn)
#define OFF_XX    2097152u    // 16384
#define OFF_XHI   2113536u    // 1048576 float-slots = 2097152 bf16 (pre-swizzled)
#define OFF_IDX   3162112u    // 147456 ints
#define OFF_O     3309568u    // 4849664 (candbuf aliases first 2097152 floats)
#define OFF_Y     8159232u    // 2097152
#define OFF_GNP   10256384u   // 131072
#define OFF_GNA   10387456u   // 512
#define OFF_GND   10387968u   // 512
#define OFF_WP    10388480u   // 65536
#define OFF_BIASP 10454016u   // 512
#define OFF_BNSUM 10454528u   // 128
#define OFF_BNSQ  10454656u   // 128
#define OFF_BNSC  10454784u   // 128
#define OFF_BNSH  10454912u   // 128

using bf16x8 = __attribute__((ext_vector_type(8))) short;
using f32x4  = __attribute__((ext_vector_type(4))) float;

typedef __attribute__((address_space(1))) const unsigned as1c_u32;
typedef __attribute__((address_space(3))) unsigned as3_u32;

static __device__ __forceinline__ unsigned umax_(unsigned a, unsigned b) { return a > b ? a : b; }
static __device__ __forceinline__ unsigned umin_(unsigned a, unsigned b) { return a > b ? b : a; }

// ---------------- K1: transpose [B,C,N] -> xt [B*N,C] fp32 + pre-swizzled bf16 xhi + xx ----
// xhi swizzle: 16B granule g (8 bf16) of row R stored at slot g ^ (R&15), so a LINEAR
// global->LDS DMA of a 128-row chunk reproduces the conflict-free swizzled LDS layout.
__global__ void k_transpose(const float* __restrict__ x, float* __restrict__ xt,
                            __hip_bfloat16* __restrict__ xhi, float* __restrict__ xx) {
  __shared__ float t[32][33];
  int tx = threadIdx.x, ty = threadIdx.y;
  int n0 = blockIdx.x * 32, c0 = blockIdx.y * 32, b = blockIdx.z;
  float v = x[((size_t)b * CCH + c0 + ty) * NPTS + n0 + tx];
  t[ty][tx] = v;
  __syncthreads();
  float tv = t[tx][ty];
  size_t R = (size_t)b * NPTS + n0 + ty;
  int c = c0 + tx;
  xt[R * CCH + c] = tv;
  int g = c >> 3, w = c & 7;
  int sc = (((g ^ ((n0 + ty) & 15)) << 3) | w);
  xhi[R * CCH + sc] = __float2bfloat16(tv);
  if (ty == 0) {
    float s = 0.f;
    #pragma unroll
    for (int k = 0; k < 32; k++) { float u = t[k][tx]; s += u * u; }
    atomicAdd(&xx[b * NPTS + n0 + tx], s);
  }
}

// ---------------- K2: MFMA Gram (bf16) + fused per-lane packed top-8 (BRANCHLESS) -------
// 256 thr = 4 waves, 32 queries/block (q-frags in regs), 128-cand chunks.
// Staging: async global_load_lds (width 16) into double-buffered LDS (xhi pre-swizzled).
// Selection: packed uint = 20 key bits (monotone-mapped fp32) | 12 idx bits, sorted
// 8-reg insert via v_max_u32/v_min_u32 every key (64-lane waves make the "skip if below
// threshold" branch useless: P(any lane inserts) ~= 1, measured VALUBusy 65% in R5).
__launch_bounds__(256, 2)
__global__ void k_knn(const short* __restrict__ xhi, const float* __restrict__ xx,
                      unsigned* __restrict__ cand) {
  __shared__ short Acs[2][16384]; // 2 x 32 KB
  const int tid = threadIdx.x;
  const int wave = tid >> 6, lane = tid & 63;
  const int quad = lane >> 4, m = lane & 15;
  const int b = blockIdx.y;
  const int q0 = blockIdx.x * 32;
  const short* xb = xhi + (size_t)b * NPTS * CCH;
  const float* xxb = xx + (b << 12);

  const char* gsrc0 = (const char*)xb + wave * 8192 + lane * 16;

  // prologue: stage chunk 0 into buffer 0
  #pragma unroll
  for (int i = 0; i < 8; i++)
    __builtin_amdgcn_global_load_lds((as1c_u32*)(gsrc0 + i * 1024),
                                     (as3_u32*)&Acs[0][wave * 4096 + i * 512],
                                     16, 0, 0);

  // query B-frags (un-swizzle: granule ks*4+quad at slot ^(row&15), row&15==m)
  bf16x8 qfrag[2][4];
  #pragma unroll
  for (int qt = 0; qt < 2; qt++) {
    const short* qrow = xb + (size_t)(q0 + qt * 16 + m) * CCH;
    #pragma unroll
    for (int ks = 0; ks < 4; ks++) {
      int slot = (ks * 4 + quad) ^ m;
      qfrag[qt][ks] = *(const bf16x8*)(qrow + slot * 8);
    }
  }

  // 0u sentinel is safe: every real packed candidate > 0 (keys finite), and each lane
  // sees 256 real candidates so all 8 slots fill. No threshold, no reverse map.
  unsigned top8[2][8];
  #pragma unroll
  for (int qt = 0; qt < 2; qt++)
    #pragma unroll
    for (int p = 0; p < 8; p++) top8[qt][p] = 0u;

  const unsigned vIdx = (unsigned)(wave * 32 + quad * 4);
  const f32x4 zero4 = {0.f, 0.f, 0.f, 0.f};

  for (int c = 0; c < 32; c++) {
    __syncthreads(); // drains chunk-c DMA (and prior ds_reads)
    if (c < 31) {
      const char* gsrc = gsrc0 + (size_t)(c + 1) * 32768;
      int bi = (c + 1) & 1;
      #pragma unroll
      for (int i = 0; i < 8; i++)
        __builtin_amdgcn_global_load_lds((as1c_u32*)(gsrc + i * 1024),
                                         (as3_u32*)&Acs[bi][wave * 4096 + i * 512],
                                         16, 0, 0);
    }
    float xv[2][4];
    #pragma unroll
    for (int ct = 0; ct < 2; ct++)
      #pragma unroll
      for (int r = 0; r < 4; r++)
        xv[ct][r] = xxb[c * 128 + wave * 32 + ct * 16 + quad * 4 + r];

    const short* cur = &Acs[c & 1][0];
    f32x4 acc[2][2];
    #pragma unroll
    for (int ct = 0; ct < 2; ct++)
      #pragma unroll
      for (int qt = 0; qt < 2; qt++) acc[ct][qt] = zero4;

    #pragma unroll
    for (int ks = 0; ks < 4; ks++) {
      bf16x8 af[2];
      #pragma unroll
      for (int ct = 0; ct < 2; ct++) {
        int row = wave * 32 + ct * 16 + m;
        int slot = (ks * 4 + quad) ^ m;
        af[ct] = *(const bf16x8*)&cur[row * 128 + slot * 8];
      }
      #pragma unroll
      for (int ct = 0; ct < 2; ct++)
        #pragma unroll
        for (int qt = 0; qt < 2; qt++)
          acc[ct][qt] = __builtin_amdgcn_mfma_f32_16x16x32_bf16(
              af[ct], qfrag[qt][ks], acc[ct][qt], 0, 0, 0);
    }

    // branchless selection: ~21 VALU/key (fma + 3-op map + 2-op pack + 15 max/min)
    const unsigned cbase = vIdx + (unsigned)(c * 128);
    #pragma unroll
    for (int ct = 0; ct < 2; ct++) {
      #pragma unroll
      for (int r = 0; r < 4; r++) {
        unsigned ci = cbase + (unsigned)(ct * 16 + r);
        #pragma unroll
        for (int qt = 0; qt < 2; qt++) {
          float key = fmaf(2.f, acc[ct][qt][r], -xv[ct][r]);
          unsigned u = __float_as_uint(key);
          u ^= ((unsigned)((int)u >> 31)) | 0x80000000u;
          unsigned cv = (u & 0xFFFFF000u) | ci;
          #pragma unroll
          for (int p = 0; p < 8; p++) {
            unsigned t = top8[qt][p];
            top8[qt][p] = umax_(t, cv);
            cv = umin_(t, cv);
          }
        }
      }
    }
  }

  int slot = wave * 4 + quad;
  #pragma unroll
  for (int qt = 0; qt < 2; qt++) {
    int q = q0 + qt * 16 + m;
    unsigned* dst = cand + ((size_t)((b << 12) + q) * 16 + slot) * 8;
    #pragma unroll
    for (int p = 0; p < 8; p++) dst[p] = top8[qt][p];
  }
}

// ---------------- K2b: merge 128 packed -> top-16 -> exact fp32 re-rank -> top-9 --------
__launch_bounds__(256)
__global__ void k_rerank(const unsigned* __restrict__ cand, const float* __restrict__ xt,
                         const float* __restrict__ xx, int* __restrict__ idxOut) {
  __shared__ __align__(16) unsigned arr[4][128];
  __shared__ int selS[4][16];
  __shared__ float keyS[4][16];
  int tid = threadIdx.x, wave = tid >> 6, lane = tid & 63;
  int qg = blockIdx.x * 4 + wave;
  int b = qg >> 12;
  const unsigned* src = cand + (size_t)qg * 128;
  unsigned e1 = src[lane], e2 = src[lane + 64];
  arr[wave][lane] = e1; arr[wave][lane + 64] = e2;
  __syncthreads();
  int r1 = 0, r2 = 0;
  #pragma unroll 8
  for (int f = 0; f < 128; f += 4) {
    uint4 fv = *(const uint4*)&arr[wave][f];
    r1 += (fv.x > e1) + (fv.y > e1) + (fv.z > e1) + (fv.w > e1);
    r2 += (fv.x > e2) + (fv.y > e2) + (fv.z > e2) + (fv.w > e2);
  }
  if (r1 < 16) selS[wave][r1] = (int)(e1 & 0xFFFu);
  if (r2 < 16) selS[wave][r2] = (int)(e2 & 0xFFFu);
  __syncthreads();
  // exact fp32 keys: 4 lanes per candidate, 32 channels each
  int cnum = lane >> 2, part = lane & 3;
  int cidx = selS[wave][cnum];
  const float* rq = xt + (size_t)qg * CCH;
  const float* rc = xt + ((size_t)(b << 12) + cidx) * CCH;
  float dot = 0.f;
  #pragma unroll
  for (int j = 0; j < 8; j++) {
    float4 a4 = *(const float4*)&rq[part * 32 + j * 4];
    float4 c4 = *(const float4*)&rc[part * 32 + j * 4];
    dot += a4.x * c4.x + a4.y * c4.y + a4.z * c4.z + a4.w * c4.w;
  }
  dot += __shfl_xor(dot, 1);
  dot += __shfl_xor(dot, 2);
  if (part == 0)
    keyS[wave][cnum] = fmaf(2.f, dot, -xx[(b << 12) + cidx]);
  __syncthreads();
  if (lane < 16) {
    float k = keyS[wave][lane]; int i = selS[wave][lane];
    int r = 0;
    #pragma unroll
    for (int f = 0; f < 16; f++) {
      float fk = keyS[wave][f]; int fi = selS[wave][f];
      r += (fk > k) || (fk == k && fi < i);
    }
    if (r < 9) idxOut[(size_t)qg * 9 + r] = i;
  }
}

// ---------------- K3: O[pos][0:128]=u=(Wa+Wb)x+b_lin, [128:256]=v=Wb x, [256:292]=aw ----
__launch_bounds__(256)
__global__ void k_linear(const float* __restrict__ xt, const float* __restrict__ w_lin,
                         const float* __restrict__ b_lin, const float* __restrict__ w_aw,
                         const float* __restrict__ b_aw, float* __restrict__ O) {
  __shared__ __align__(16) float Xs[64 * 132];
  __shared__ __align__(16) float Ws[64 * 132];
  int tid = threadIdx.x;
  int tx = tid & 15, ty = tid >> 4;
  int p0 = blockIdx.x * 64, o0 = blockIdx.y * 64;
  #pragma unroll
  for (int i = 0; i < 8; i++) {
    int flat = tid + i * 256; int r = flat >> 5, c4 = flat & 31;
    *(float4*)&Xs[r * 132 + c4 * 4] = *(const float4*)&xt[(size_t)(p0 + r) * CCH + c4 * 4];
  }
  #pragma unroll
  for (int i = 0; i < 8; i++) {
    int flat = tid + i * 256; int r = flat >> 5, c4 = flat & 31;
    int o = o0 + r; float4 v;
    if (o < 128) {
      float4 a = *(const float4*)&w_lin[(size_t)o * 256 + c4 * 4];
      float4 c = *(const float4*)&w_lin[(size_t)o * 256 + 128 + c4 * 4];
      v = make_float4(a.x + c.x, a.y + c.y, a.z + c.z, a.w + c.w);
    } else if (o < 256) {
      v = *(const float4*)&w_lin[(size_t)(o - 128) * 256 + 128 + c4 * 4];
    } else if (o < 292) {
      v = *(const float4*)&w_aw[(size_t)(o - 256) * 128 + c4 * 4];
    } else v = make_float4(0.f, 0.f, 0.f, 0.f);
    *(float4*)&Ws[r * 132 + c4 * 4] = v;
  }
  __syncthreads();
  float acc[4][4] = {};
  #pragma unroll 2
  for (int kq = 0; kq < 32; kq++) {
    float4 xa[4], wb[4];
    #pragma unroll
    for (int i = 0; i < 4; i++) xa[i] = *(const float4*)&Xs[(ty * 4 + i) * 132 + kq * 4];
    #pragma unroll
    for (int j = 0; j < 4; j++) wb[j] = *(const float4*)&Ws[(tx + 16 * j) * 132 + kq * 4];
    #pragma unroll
    for (int i = 0; i < 4; i++)
      #pragma unroll
      for (int j = 0; j < 4; j++)
        acc[i][j] += xa[i].x * wb[j].x + xa[i].y * wb[j].y + xa[i].z * wb[j].z + xa[i].w * wb[j].w;
  }
  #pragma unroll
  for (int j = 0; j < 4; j++) {
    int o = o0 + tx + 16 * j;
    if (o < 292) {
      float bias = (o < 128) ? b_lin[o] : ((o < 256) ? 0.f : b_aw[o - 256]);
      #pragma unroll
      for (int i = 0; i < 4; i++)
        O[(size_t)(p0 + ty * 4 + i) * 296 + o] = acc[i][j] + bias;
    }
  }
}

// ---------------- K4: per-point grouped attention, residual, GN partials ----------------
// fE removed (elu at use): LDS 46->27 KB => ~5 blocks/CU for this gather-bound kernel.
__launch_bounds__(256)
__global__ void k_attn(const float* __restrict__ O, const int* __restrict__ idxArr,
                       const float* __restrict__ xt, float* __restrict__ Y,
                       float* __restrict__ gnPart) {
  __shared__ __align__(16) float fF[4][1188];
  __shared__ __align__(16) float scS[4][432];
  __shared__ float awS[4][48];
  __shared__ float w9S[4][48];
  __shared__ int tI[45], tJ[45];
  int tid = threadIdx.x;
  int wave = tid >> 6, l = tid & 63;
  int pos = blockIdx.x * 4 + wave;
  int b = pos >> 12;
  if (tid == 0) {
    int p = 0;
    for (int i = 0; i < 9; i++) for (int j = i; j < 9; j++) { tI[p] = i; tJ[p] = j; p++; }
  }
  int nbr[9];
  const float* Op = O + (size_t)pos * 296;
  #pragma unroll
  for (int k = 0; k < 9; k++) nbr[k] = idxArr[(size_t)pos * 9 + k];
  float2 u = *(const float2*)(Op + 2 * l);
  float* fFw = fF[wave];
  #pragma unroll
  for (int k = 0; k < 9; k++) {
    const float* vp = O + (size_t)((b << 12) + nbr[k]) * 296 + 128;
    float2 vv = *(const float2*)(vp + 2 * l);
    *(float2*)&fFw[k * 132 + 2 * l] = make_float2(u.x - vv.x, u.y - vv.y);
  }
  __syncthreads();
  #pragma unroll
  for (int r = 0; r < 3; r++) {
    int p = r * 64 + l;
    if (p < 180) {
      int g = p / 45, q = p - g * 45;
      int i = tI[q], j = tJ[q];
      const float* fi = fFw + i * 132 + g * 32;
      const float* fj = fFw + j * 132 + g * 32;
      float s = 0.f;
      #pragma unroll
      for (int t8 = 0; t8 < 8; t8++) {
        float4 a4 = *(const float4*)(fi + 4 * t8);
        float4 b4 = *(const float4*)(fj + 4 * t8);
        s += a4.x * b4.x + a4.y * b4.y + a4.z * b4.z + a4.w * b4.w;
      }
      s *= 0.17677669529663687f; // 1/sqrt(32)
      scS[wave][(g * 9 + i) * 12 + j] = s;
      scS[wave][(g * 9 + j) * 12 + i] = s;
    }
  }
  __syncthreads();
  if (l < 36) {
    int g = l / 9, i = l - g * 9;
    float* rp = &scS[wave][(g * 9 + i) * 12];
    float mx = rp[0];
    #pragma unroll
    for (int j = 1; j < 9; j++) mx = fmaxf(mx, rp[j]);
    float e[9]; float sm = 0.f;
    #pragma unroll
    for (int j = 0; j < 9; j++) { e[j] = __expf(rp[j] - mx); sm += e[j]; }
    float inv = 1.f / sm;
    #pragma unroll
    for (int j = 0; j < 9; j++) rp[j] = e[j] * inv;
  } else if (l < 40) {
    int g = l - 36;
    float a[9]; float mx = -3.4e38f;
    #pragma unroll
    for (int k = 0; k < 9; k++) { a[k] = Op[256 + g * 9 + k]; mx = fmaxf(mx, a[k]); }
    float sm = 0.f;
    #pragma unroll
    for (int k = 0; k < 9; k++) { a[k] = __expf(a[k] - mx); sm += a[k]; }
    float inv = 1.f / sm;
    #pragma unroll
    for (int k = 0; k < 9; k++) awS[wave][g * 12 + k] = a[k] * inv;
  }
  __syncthreads();
  if (l < 36) {
    int g = l / 9, j = l - g * 9;
    float s = 0.f;
    #pragma unroll
    for (int i = 0; i < 9; i++) s += awS[wave][g * 12 + i] * scS[wave][(g * 9 + i) * 12 + j];
    w9S[wave][g * 12 + j] = s;
  }
  __syncthreads();
  int g = l >> 4;
  float w9r[9];
  #pragma unroll
  for (int j = 0; j < 9; j++) w9r[j] = w9S[wave][g * 12 + j];
  int c0 = 2 * l;
  float lf0 = 0.f, lf1 = 0.f;
  #pragma unroll
  for (int j = 0; j < 9; j++) {
    float2 f2 = *(const float2*)&fFw[j * 132 + c0];
    float e0 = f2.x > 0.f ? f2.x : __expf(f2.x) - 1.f;
    float e1 = f2.y > 0.f ? f2.y : __expf(f2.y) - 1.f;
    lf0 += w9r[j] * e0;
    lf1 += w9r[j] * e1;
  }
  float2 xv = *(const float2*)(xt + (size_t)pos * CCH + c0);
  float y0 = lf0 + xv.x, y1 = lf1 + xv.y;
  *(float2*)(Y + (size_t)pos * CCH + c0) = make_float2(y0, y1);
  float s1 = y0 + y1, s2 = y0 * y0 + y1 * y1;
  #pragma unroll
  for (int mm = 1; mm <= 8; mm <<= 1) { s1 += __shfl_xor(s1, mm); s2 += __shfl_xor(s2, mm); }
  if ((l & 15) == 0) {
    gnPart[(size_t)pos * 8 + g * 2]     = s1;
    gnPart[(size_t)pos * 8 + g * 2 + 1] = s2;
  }
}

// ---------------- K5: GN stats -> per (b,c) affine a,d ----------------
__global__ void k_gnstats(const float* __restrict__ gnPart,
                          const float* __restrict__ gn_g, const float* __restrict__ gn_b,
                          float* __restrict__ gnA, float* __restrict__ gnD) {
  int bg = blockIdx.x; int b = bg >> 2, g = bg & 3;
  int tid = threadIdx.x;
  float s1 = 0.f, s2 = 0.f;
  for (int r = tid; r < NPTS; r += 256) {
    const float* p = gnPart + (size_t)(b * NPTS + r) * 8 + g * 2;
    s1 += p[0]; s2 += p[1];
  }
  __shared__ float r1[256], r2[256];
  r1[tid] = s1; r2[tid] = s2;
  __syncthreads();
  for (int off = 128; off > 0; off >>= 1) {
    if (tid < off) { r1[tid] += r1[tid + off]; r2[tid] += r2[tid + off]; }
    __syncthreads();
  }
  __shared__ float muS, rsS;
  if (tid == 0) {
    float mu = r1[0] * (1.f / 131072.f);
    float var = r2[0] * (1.f / 131072.f) - mu * mu;
    muS = mu; rsS = 1.f / sqrtf(var + 1e-5f);
  }
  __syncthreads();
  if (tid < 32) {
    int c = g * 32 + tid;
    float a = rsS * gn_g[c];
    gnA[b * 128 + c] = a;
    gnD[b * 128 + c] = gn_b[c] - muS * a;
  }
}

// ---------------- K5b: fold GN affine into conv weights per batch ----------------
__global__ void k_fold(const float* __restrict__ conv_w, const float* __restrict__ conv_b,
                       const float* __restrict__ gnA, const float* __restrict__ gnD,
                       float* __restrict__ Wp, float* __restrict__ biasp) {
  int b = blockIdx.x; int tid = threadIdx.x;
  __shared__ float dS[128], aS[128];
  if (tid < 128) { dS[tid] = gnD[b * 128 + tid]; aS[tid] = gnA[b * 128 + tid]; }
  __syncthreads();
  for (int f = tid; f < 16384; f += 256)
    Wp[(size_t)b * 16384 + f] = conv_w[f] * aS[f & 127];
  if (tid < 128) {
    float s = conv_b[tid];
    for (int c = 0; c < 128; c++) s += conv_w[tid * 128 + c] * dS[c];
    biasp[b * 128 + tid] = s;
  }
}

// ---------------- K6: conv GEMM on raw y + BN partial sums ----------------
__launch_bounds__(256)
__global__ void k_conv(const float* __restrict__ Y, const float* __restrict__ Wp,
                       const float* __restrict__ biasp, float* __restrict__ zpre,
                       float* __restrict__ bnSum, float* __restrict__ bnSq) {
  __shared__ __align__(16) float Ys[64 * 132];
  __shared__ __align__(16) float Ws[64 * 132];
  int tid = threadIdx.x;
  int tx = tid & 15, ty = tid >> 4;
  int n0 = blockIdx.x * 64, o0 = blockIdx.y * 64, b = blockIdx.z;
  #pragma unroll
  for (int i = 0; i < 8; i++) {
    int flat = tid + i * 256; int r = flat >> 5, c4 = flat & 31;
    *(float4*)&Ys[r * 132 + c4 * 4] = *(const float4*)&Y[(size_t)((b << 12) + n0 + r) * CCH + c4 * 4];
    *(float4*)&Ws[r * 132 + c4 * 4] = *(const float4*)&Wp[(size_t)b * 16384 + (size_t)(o0 + r) * 128 + c4 * 4];
  }
  __syncthreads();
  float acc[4][4] = {};
  #pragma unroll 2
  for (int kq = 0; kq < 32; kq++) {
    float4 wa[4], yb[4];
    #pragma unroll
    for (int i = 0; i < 4; i++) wa[i] = *(const float4*)&Ws[(ty * 4 + i) * 132 + kq * 4];
    #pragma unroll
    for (int j = 0; j < 4; j++) yb[j] = *(const float4*)&Ys[(tx + 16 * j) * 132 + kq * 4];
    #pragma unroll
    for (int i = 0; i < 4; i++)
      #pragma unroll
      for (int j = 0; j < 4; j++)
        acc[i][j] += wa[i].x * yb[j].x + wa[i].y * yb[j].y + wa[i].z * yb[j].z + wa[i].w * yb[j].w;
  }
  #pragma unroll
  for (int i = 0; i < 4; i++) {
    int o = o0 + ty * 4 + i;
    float bias = biasp[b * 128 + o];
    float p1 = 0.f, p2 = 0.f;
    #pragma unroll
    for (int j = 0; j < 4; j++) {
      float z = acc[i][j] + bias;
      zpre[(((size_t)((b << 7) + o)) << 12) + n0 + tx + 16 * j] = z;
      p1 += z; p2 += z * z;
    }
    #pragma unroll
    for (int mm = 1; mm <= 8; mm <<= 1) { p1 += __shfl_xor(p1, mm); p2 += __shfl_xor(p2, mm); }
    if (tx == 0) { atomicAdd(&bnSum[o], p1); atomicAdd(&bnSq[o], p2); }
  }
}

// ---------------- K7a: BN finalize ----------------
__global__ void k_bnfin(const float* __restrict__ bnSum, const float* __restrict__ bnSq,
                        const float* __restrict__ bn_g, const float* __restrict__ bn_b,
                        float* __restrict__ bnScale, float* __restrict__ bnShift) {
  int o = threadIdx.x;
  float m = bnSum[o] * (1.f / 16384.f);
  float v = bnSq[o] * (1.f / 16384.f) - m * m;
  float sc = bn_g[o] / sqrtf(v + 1e-5f);
  bnScale[o] = sc;
  bnShift[o] = bn_b[o] - m * sc;
}

// ---------------- K7b: normalize + ReLU -> d_out ----------------
__global__ void k_final(const float* __restrict__ zpre, const float* __restrict__ bnScale,
                        const float* __restrict__ bnShift, float* __restrict__ out) {
  int i4 = blockIdx.x * 256 + threadIdx.x;
  int e = i4 * 4;
  int o = (e >> 12) & 127;
  float4 z = *(const float4*)&zpre[e];
  float sc = bnScale[o], sh = bnShift[o];
  float4 r;
  r.x = fmaxf(fmaf(z.x, sc, sh), 0.f);
  r.y = fmaxf(fmaf(z.y, sc, sh), 0.f);
  r.z = fmaxf(fmaf(z.z, sc, sh), 0.f);
  r.w = fmaxf(fmaf(z.w, sc, sh), 0.f);
  *(float4*)&out[e] = r;
}

extern "C" void kernel_launch(void* const* d_in, const int* in_sizes, int n_in,
                              void* d_out, int out_size, void* d_ws, size_t ws_size,
                              hipStream_t stream) {
  const float* features = (const float*)d_in[0];
  const float* w_lin  = (const float*)d_in[1];
  const float* b_lin  = (const float*)d_in[2];
  const float* w_aw   = (const float*)d_in[3];
  const float* b_aw   = (const float*)d_in[4];
  const float* gn_g   = (const float*)d_in[5];
  const float* gn_b   = (const float*)d_in[6];
  const float* conv_w = (const float*)d_in[7];
  const float* conv_b = (const float*)d_in[8];
  const float* bn_g   = (const float*)d_in[9];
  const float* bn_b   = (const float*)d_in[10];

  float* ws    = (float*)d_ws;
  float* xt    = ws + OFF_XT;
  float* xxp   = ws + OFF_XX;
  __hip_bfloat16* xhip = (__hip_bfloat16*)(ws + OFF_XHI);
  int*   idxp  = (int*)(ws + OFF_IDX);
  float* Op    = ws + OFF_O;
  unsigned* candp = (unsigned*)(ws + OFF_O);   // alias: dead before k_linear writes O
  float* Yp    = ws + OFF_Y;
  float* gnp   = ws + OFF_GNP;
  float* gnA   = ws + OFF_GNA;
  float* gnD   = ws + OFF_GND;
  float* Wp    = ws + OFF_WP;
  float* biasp = ws + OFF_BIASP;
  float* bnSum = ws + OFF_BNSUM;
  float* bnSq  = ws + OFF_BNSQ;
  float* bnSc  = ws + OFF_BNSC;
  float* bnSh  = ws + OFF_BNSH;
  float* zpre  = xt; // alias: xt dead after k_attn

  hipMemsetAsync(xxp, 0, NPTS * BB * sizeof(float), stream);
  hipMemsetAsync(bnSum, 0, 256 * sizeof(float), stream); // bnSum + bnSq contiguous

  k_transpose<<<dim3(128, 4, 4), dim3(32, 32), 0, stream>>>(features, xt, xhip, xxp);
  k_knn<<<dim3(128, 4), 256, 0, stream>>>((const short*)xhip, xxp, candp);
  k_rerank<<<4096, 256, 0, stream>>>(candp, xt, xxp, idxp);
  k_linear<<<dim3(256, 5), 256, 0, stream>>>(xt, w_lin, b_lin, w_aw, b_aw, Op);
  k_attn<<<4096, 256, 0, stream>>>(Op, idxp, xt, Yp, gnp);
  k_gnstats<<<16, 256, 0, stream>>>(gnp, gn_g, gn_b, gnA, gnD);
  k_fold<<<4, 256, 0, stream>>>(conv_w, conv_b, gnA, gnD, Wp, biasp);
  k_conv<<<dim3(64, 2, 4), 256, 0, stream>>>(Yp, Wp, biasp, zpre, bnSum, bnSq);
  k_bnfin<<<1, 128, 0, stream>>>(bnSum, bnSq, bn_g, bn_b, bnSc, bnSh);
  k_final<<<2048, 256, 0, stream>>>(zpre, bnSc, bnSh, (float*)d_out);
}

// Round 9
// 276.777 us; speedup vs baseline: 3.8937x; 1.0744x over previous
//
#include <hip/hip_runtime.h>
#include <hip/hip_bf16.h>
#include <cstddef>

// Problem constants
#define NPTS 4096
#define CCH  128
#define KNN  9
#define GRP  4
#define BB   4
// workspace layout (float offsets)
#define OFF_XT    0u          // 2097152 floats (reused as zpre after k_attn)
#define OFF_XX    2097152u    // 16384
#define OFF_XHI   2113536u    // 1048576 float-slots = 2097152 bf16 (pre-swizzled)
#define OFF_IDX   3162112u    // 147456 ints
#define OFF_O     3309568u    // 4849664 (candbuf aliases first 2097152 floats)
#define OFF_Y     8159232u    // 2097152
#define OFF_GNP   10256384u   // 131072
#define OFF_GNA   10387456u   // 512
#define OFF_GND   10387968u   // 512
#define OFF_WP    10388480u   // 65536
#define OFF_BIASP 10454016u   // 512
#define OFF_BNSUM 10454528u   // 128
#define OFF_BNSQ  10454656u   // 128
#define OFF_BNSC  10454784u   // 128
#define OFF_BNSH  10454912u   // 128

using bf16x8 = __attribute__((ext_vector_type(8))) short;
using f32x4  = __attribute__((ext_vector_type(4))) float;

typedef __attribute__((address_space(1))) const unsigned as1c_u32;
typedef __attribute__((address_space(3))) unsigned as3_u32;

// compare-exchange, descending (a keeps max) — v_max_f32/v_min_f32, parallel ILP
#define CE(a, b) { float _h = fmaxf(a, b); b = fminf(a, b); a = _h; }

// Sentinel: packed(-FLT_MAX, idx=0) = 0xFF7FF000 — finite huge-negative float,
// always below any real packed key (|key| <= O(100)); never NaN.
#define SENT_BITS 0xFF7FF000u

// ---------------- K1: transpose [B,C,N] -> xt [B*N,C] fp32 + pre-swizzled bf16 xhi + xx ----
// xhi swizzle: 16B granule g (8 bf16) of row R stored at slot g ^ (R&15), so a LINEAR
// global->LDS DMA of a 128-row chunk reproduces the conflict-free swizzled LDS layout.
__global__ void k_transpose(const float* __restrict__ x, float* __restrict__ xt,
                            __hip_bfloat16* __restrict__ xhi, float* __restrict__ xx) {
  __shared__ float t[32][33];
  int tx = threadIdx.x, ty = threadIdx.y;
  int n0 = blockIdx.x * 32, c0 = blockIdx.y * 32, b = blockIdx.z;
  float v = x[((size_t)b * CCH + c0 + ty) * NPTS + n0 + tx];
  t[ty][tx] = v;
  __syncthreads();
  float tv = t[tx][ty];
  size_t R = (size_t)b * NPTS + n0 + ty;
  int c = c0 + tx;
  xt[R * CCH + c] = tv;
  int g = c >> 3, w = c & 7;
  int sc = (((g ^ ((n0 + ty) & 15)) << 3) | w);
  xhi[R * CCH + sc] = __float2bfloat16(tv);
  if (ty == 0) {
    float s = 0.f;
    #pragma unroll
    for (int k = 0; k < 32; k++) { float u = t[k][tx]; s += u * u; }
    atomicAdd(&xx[b * NPTS + n0 + tx], s);
  }
}

// ---------------- K2: MFMA Gram (bf16) + per-chunk sort-network top-8 ----------------
// 256 thr = 4 waves, 32 queries/block (q-frags in regs), 128-cand chunks.
// Staging: async global_load_lds (width 16) into double-buffered LDS (xhi pre-swizzled).
// Rank key = inner - xx/2 (monotone in pd): xx folded into the MFMA C operand, so no
// per-key fma. Keys pack the candidate index into the low 12 mantissa bits and are
// selected with fp32 compare networks: Batcher sort-8 (19 CE) per chunk + bitonic
// keep-top-8 merge (8 max + 12 CE). ~11 ops/key, shallow chains (R7 showed the serial
// 16-deep insert chain was latency-bound at 54% VALUBusy).
__launch_bounds__(256, 2)
__global__ void k_knn(const short* __restrict__ xhi, const float* __restrict__ xx,
                      float* __restrict__ cand) {
  __shared__ short Acs[2][16384]; // 2 x 32 KB
  const int tid = threadIdx.x;
  const int wave = tid >> 6, lane = tid & 63;
  const int quad = lane >> 4, m = lane & 15;
  const int b = blockIdx.y;
  const int q0 = blockIdx.x * 32;
  const short* xb = xhi + (size_t)b * NPTS * CCH;
  const float* xxb = xx + (b << 12);

  const char* gsrc0 = (const char*)xb + wave * 8192 + lane * 16;

  // prologue: stage chunk 0 into buffer 0
  #pragma unroll
  for (int i = 0; i < 8; i++)
    __builtin_amdgcn_global_load_lds((as1c_u32*)(gsrc0 + i * 1024),
                                     (as3_u32*)&Acs[0][wave * 4096 + i * 512],
                                     16, 0, 0);

  // query B-frags (un-swizzle: granule ks*4+quad at slot ^(row&15), row&15==m)
  bf16x8 qfrag[2][4];
  #pragma unroll
  for (int qt = 0; qt < 2; qt++) {
    const short* qrow = xb + (size_t)(q0 + qt * 16 + m) * CCH;
    #pragma unroll
    for (int ks = 0; ks < 4; ks++) {
      int slot = (ks * 4 + quad) ^ m;
      qfrag[qt][ks] = *(const bf16x8*)(qrow + slot * 8);
    }
  }

  float top8[2][8];
  #pragma unroll
  for (int qt = 0; qt < 2; qt++)
    #pragma unroll
    for (int p = 0; p < 8; p++) top8[qt][p] = __uint_as_float(SENT_BITS);

  for (int c = 0; c < 32; c++) {
    __syncthreads(); // drains chunk-c DMA and prior buffer reads
    if (c < 31) {
      const char* gsrc = gsrc0 + (size_t)(c + 1) * 32768;
      int bi = (c + 1) & 1;
      #pragma unroll
      for (int i = 0; i < 8; i++)
        __builtin_amdgcn_global_load_lds((as1c_u32*)(gsrc + i * 1024),
                                         (as3_u32*)&Acs[bi][wave * 4096 + i * 512],
                                         16, 0, 0);
    }
    // fold -xx/2 into the accumulator init (C operand); query-independent per row
    f32x4 cinit[2];
    #pragma unroll
    for (int ct = 0; ct < 2; ct++)
      #pragma unroll
      for (int r = 0; r < 4; r++)
        cinit[ct][r] = -0.5f * xxb[c * 128 + wave * 32 + ct * 16 + quad * 4 + r];

    const short* cur = &Acs[c & 1][0];
    f32x4 acc[2][2];
    #pragma unroll
    for (int ct = 0; ct < 2; ct++)
      #pragma unroll
      for (int qt = 0; qt < 2; qt++) acc[ct][qt] = cinit[ct];

    #pragma unroll
    for (int ks = 0; ks < 4; ks++) {
      bf16x8 af[2];
      #pragma unroll
      for (int ct = 0; ct < 2; ct++) {
        int row = wave * 32 + ct * 16 + m;
        int slot = (ks * 4 + quad) ^ m;
        af[ct] = *(const bf16x8*)&cur[row * 128 + slot * 8];
      }
      #pragma unroll
      for (int ct = 0; ct < 2; ct++)
        #pragma unroll
        for (int qt = 0; qt < 2; qt++)
          acc[ct][qt] = __builtin_amdgcn_mfma_f32_16x16x32_bf16(
              af[ct], qfrag[qt][ks], acc[ct][qt], 0, 0, 0);
    }

    // selection: pack 8 keys (and+or each), Batcher sort-8, bitonic keep-top-8 merge
    const unsigned cbase = (unsigned)(c * 128 + wave * 32 + quad * 4);
    #pragma unroll
    for (int qt = 0; qt < 2; qt++) {
      float k[8];
      #pragma unroll
      for (int ct = 0; ct < 2; ct++)
        #pragma unroll
        for (int r = 0; r < 4; r++) {
          unsigned u = __float_as_uint(acc[ct][qt][r]);
          k[ct * 4 + r] = __uint_as_float((u & 0xFFFFF000u) |
                                          (cbase + (unsigned)(ct * 16 + r)));
        }
      // Batcher odd-even mergesort 8 (19 CE), descending
      CE(k[0],k[1]) CE(k[2],k[3]) CE(k[4],k[5]) CE(k[6],k[7])
      CE(k[0],k[2]) CE(k[1],k[3]) CE(k[4],k[6]) CE(k[5],k[7])
      CE(k[1],k[2]) CE(k[5],k[6])
      CE(k[0],k[4]) CE(k[1],k[5]) CE(k[2],k[6]) CE(k[3],k[7])
      CE(k[2],k[4]) CE(k[3],k[5])
      CE(k[1],k[2]) CE(k[3],k[4]) CE(k[5],k[6])
      // keep-top-8 of (sorted run) U (sorted chunk): bitonic first stage...
      float t[8];
      #pragma unroll
      for (int i = 0; i < 8; i++) t[i] = fmaxf(top8[qt][i], k[7 - i]);
      // ...then bitonic sort the (down-up) bitonic result, descending (12 CE)
      CE(t[0],t[4]) CE(t[1],t[5]) CE(t[2],t[6]) CE(t[3],t[7])
      CE(t[0],t[2]) CE(t[1],t[3]) CE(t[4],t[6]) CE(t[5],t[7])
      CE(t[0],t[1]) CE(t[2],t[3]) CE(t[4],t[5]) CE(t[6],t[7])
      #pragma unroll
      for (int i = 0; i < 8; i++) top8[qt][i] = t[i];
    }
  }

  int slot = wave * 4 + quad;
  #pragma unroll
  for (int qt = 0; qt < 2; qt++) {
    int q = q0 + qt * 16 + m;
    float* dst = cand + ((size_t)((b << 12) + q) * 16 + slot) * 8;
    #pragma unroll
    for (int p = 0; p < 8; p++) dst[p] = top8[qt][p];
  }
}

// ---------------- K2b: merge 128 packed -> top-16 -> exact fp32 re-rank -> top-9 --------
// Entries are fp32 keys with idx in low 12 mantissa bits; distinct by construction.
__launch_bounds__(256)
__global__ void k_rerank(const float* __restrict__ cand, const float* __restrict__ xt,
                         const float* __restrict__ xx, int* __restrict__ idxOut) {
  __shared__ __align__(16) float arr[4][128];
  __shared__ int selS[4][16];
  __shared__ float keyS[4][16];
  int tid = threadIdx.x, wave = tid >> 6, lane = tid & 63;
  int qg = blockIdx.x * 4 + wave;
  int b = qg >> 12;
  const float* src = cand + (size_t)qg * 128;
  float e1 = src[lane], e2 = src[lane + 64];
  arr[wave][lane] = e1; arr[wave][lane + 64] = e2;
  __syncthreads();
  int r1 = 0, r2 = 0;
  #pragma unroll 8
  for (int f = 0; f < 128; f += 4) {
    float4 fv = *(const float4*)&arr[wave][f];
    r1 += (fv.x > e1) + (fv.y > e1) + (fv.z > e1) + (fv.w > e1);
    r2 += (fv.x > e2) + (fv.y > e2) + (fv.z > e2) + (fv.w > e2);
  }
  if (r1 < 16) selS[wave][r1] = (int)(__float_as_uint(e1) & 0xFFFu);
  if (r2 < 16) selS[wave][r2] = (int)(__float_as_uint(e2) & 0xFFFu);
  __syncthreads();
  // exact fp32 keys: 4 lanes per candidate, 32 channels each
  int cnum = lane >> 2, part = lane & 3;
  int cidx = selS[wave][cnum];
  const float* rq = xt + (size_t)qg * CCH;
  const float* rc = xt + ((size_t)(b << 12) + cidx) * CCH;
  float dot = 0.f;
  #pragma unroll
  for (int j = 0; j < 8; j++) {
    float4 a4 = *(const float4*)&rq[part * 32 + j * 4];
    float4 c4 = *(const float4*)&rc[part * 32 + j * 4];
    dot += a4.x * c4.x + a4.y * c4.y + a4.z * c4.z + a4.w * c4.w;
  }
  dot += __shfl_xor(dot, 1);
  dot += __shfl_xor(dot, 2);
  if (part == 0)
    keyS[wave][cnum] = fmaf(2.f, dot, -xx[(b << 12) + cidx]);
  __syncthreads();
  if (lane < 16) {
    float k = keyS[wave][lane]; int i = selS[wave][lane];
    int r = 0;
    #pragma unroll
    for (int f = 0; f < 16; f++) {
      float fk = keyS[wave][f]; int fi = selS[wave][f];
      r += (fk > k) || (fk == k && fi < i);
    }
    if (r < 9) idxOut[(size_t)qg * 9 + r] = i;
  }
}

// ---------------- K3: O[pos][0:128]=u=(Wa+Wb)x+b_lin, [128:256]=v=Wb x, [256:292]=aw ----
__launch_bounds__(256)
__global__ void k_linear(const float* __restrict__ xt, const float* __restrict__ w_lin,
                         const float* __restrict__ b_lin, const float* __restrict__ w_aw,
                         const float* __restrict__ b_aw, float* __restrict__ O) {
  __shared__ __align__(16) float Xs[64 * 132];
  __shared__ __align__(16) float Ws[64 * 132];
  int tid = threadIdx.x;
  int tx = tid & 15, ty = tid >> 4;
  int p0 = blockIdx.x * 64, o0 = blockIdx.y * 64;
  #pragma unroll
  for (int i = 0; i < 8; i++) {
    int flat = tid + i * 256; int r = flat >> 5, c4 = flat & 31;
    *(float4*)&Xs[r * 132 + c4 * 4] = *(const float4*)&xt[(size_t)(p0 + r) * CCH + c4 * 4];
  }
  #pragma unroll
  for (int i = 0; i < 8; i++) {
    int flat = tid + i * 256; int r = flat >> 5, c4 = flat & 31;
    int o = o0 + r; float4 v;
    if (o < 128) {
      float4 a = *(const float4*)&w_lin[(size_t)o * 256 + c4 * 4];
      float4 c = *(const float4*)&w_lin[(size_t)o * 256 + 128 + c4 * 4];
      v = make_float4(a.x + c.x, a.y + c.y, a.z + c.z, a.w + c.w);
    } else if (o < 256) {
      v = *(const float4*)&w_lin[(size_t)(o - 128) * 256 + 128 + c4 * 4];
    } else if (o < 292) {
      v = *(const float4*)&w_aw[(size_t)(o - 256) * 128 + c4 * 4];
    } else v = make_float4(0.f, 0.f, 0.f, 0.f);
    *(float4*)&Ws[r * 132 + c4 * 4] = v;
  }
  __syncthreads();
  float acc[4][4] = {};
  #pragma unroll 2
  for (int kq = 0; kq < 32; kq++) {
    float4 xa[4], wb[4];
    #pragma unroll
    for (int i = 0; i < 4; i++) xa[i] = *(const float4*)&Xs[(ty * 4 + i) * 132 + kq * 4];
    #pragma unroll
    for (int j = 0; j < 4; j++) wb[j] = *(const float4*)&Ws[(tx + 16 * j) * 132 + kq * 4];
    #pragma unroll
    for (int i = 0; i < 4; i++)
      #pragma unroll
      for (int j = 0; j < 4; j++)
        acc[i][j] += xa[i].x * wb[j].x + xa[i].y * wb[j].y + xa[i].z * wb[j].z + xa[i].w * wb[j].w;
  }
  #pragma unroll
  for (int j = 0; j < 4; j++) {
    int o = o0 + tx + 16 * j;
    if (o < 292) {
      float bias = (o < 128) ? b_lin[o] : ((o < 256) ? 0.f : b_aw[o - 256]);
      #pragma unroll
      for (int i = 0; i < 4; i++)
        O[(size_t)(p0 + ty * 4 + i) * 296 + o] = acc[i][j] + bias;
    }
  }
}

// ---------------- K4: per-point grouped attention, residual, GN partials ----------------
// fE removed (elu at use): LDS 46->27 KB => ~5 blocks/CU for this gather-bound kernel.
__launch_bounds__(256)
__global__ void k_attn(const float* __restrict__ O, const int* __restrict__ idxArr,
                       const float* __restrict__ xt, float* __restrict__ Y,
                       float* __restrict__ gnPart) {
  __shared__ __align__(16) float fF[4][1188];
  __shared__ __align__(16) float scS[4][432];
  __shared__ float awS[4][48];
  __shared__ float w9S[4][48];
  __shared__ int tI[45], tJ[45];
  int tid = threadIdx.x;
  int wave = tid >> 6, l = tid & 63;
  int pos = blockIdx.x * 4 + wave;
  int b = pos >> 12;
  if (tid == 0) {
    int p = 0;
    for (int i = 0; i < 9; i++) for (int j = i; j < 9; j++) { tI[p] = i; tJ[p] = j; p++; }
  }
  int nbr[9];
  const float* Op = O + (size_t)pos * 296;
  #pragma unroll
  for (int k = 0; k < 9; k++) nbr[k] = idxArr[(size_t)pos * 9 + k];
  float2 u = *(const float2*)(Op + 2 * l);
  float* fFw = fF[wave];
  #pragma unroll
  for (int k = 0; k < 9; k++) {
    const float* vp = O + (size_t)((b << 12) + nbr[k]) * 296 + 128;
    float2 vv = *(const float2*)(vp + 2 * l);
    *(float2*)&fFw[k * 132 + 2 * l] = make_float2(u.x - vv.x, u.y - vv.y);
  }
  __syncthreads();
  #pragma unroll
  for (int r = 0; r < 3; r++) {
    int p = r * 64 + l;
    if (p < 180) {
      int g = p / 45, q = p - g * 45;
      int i = tI[q], j = tJ[q];
      const float* fi = fFw + i * 132 + g * 32;
      const float* fj = fFw + j * 132 + g * 32;
      float s = 0.f;
      #pragma unroll
      for (int t8 = 0; t8 < 8; t8++) {
        float4 a4 = *(const float4*)(fi + 4 * t8);
        float4 b4 = *(const float4*)(fj + 4 * t8);
        s += a4.x * b4.x + a4.y * b4.y + a4.z * b4.z + a4.w * b4.w;
      }
      s *= 0.17677669529663687f; // 1/sqrt(32)
      scS[wave][(g * 9 + i) * 12 + j] = s;
      scS[wave][(g * 9 + j) * 12 + i] = s;
    }
  }
  __syncthreads();
  if (l < 36) {
    int g = l / 9, i = l - g * 9;
    float* rp = &scS[wave][(g * 9 + i) * 12];
    float mx = rp[0];
    #pragma unroll
    for (int j = 1; j < 9; j++) mx = fmaxf(mx, rp[j]);
    float e[9]; float sm = 0.f;
    #pragma unroll
    for (int j = 0; j < 9; j++) { e[j] = __expf(rp[j] - mx); sm += e[j]; }
    float inv = 1.f / sm;
    #pragma unroll
    for (int j = 0; j < 9; j++) rp[j] = e[j] * inv;
  } else if (l < 40) {
    int g = l - 36;
    float a[9]; float mx = -3.4e38f;
    #pragma unroll
    for (int k = 0; k < 9; k++) { a[k] = Op[256 + g * 9 + k]; mx = fmaxf(mx, a[k]); }
    float sm = 0.f;
    #pragma unroll
    for (int k = 0; k < 9; k++) { a[k] = __expf(a[k] - mx); sm += a[k]; }
    float inv = 1.f / sm;
    #pragma unroll
    for (int k = 0; k < 9; k++) awS[wave][g * 12 + k] = a[k] * inv;
  }
  __syncthreads();
  if (l < 36) {
    int g = l / 9, j = l - g * 9;
    float s = 0.f;
    #pragma unroll
    for (int i = 0; i < 9; i++) s += awS[wave][g * 12 + i] * scS[wave][(g * 9 + i) * 12 + j];
    w9S[wave][g * 12 + j] = s;
  }
  __syncthreads();
  int g = l >> 4;
  float w9r[9];
  #pragma unroll
  for (int j = 0; j < 9; j++) w9r[j] = w9S[wave][g * 12 + j];
  int c0 = 2 * l;
  float lf0 = 0.f, lf1 = 0.f;
  #pragma unroll
  for (int j = 0; j < 9; j++) {
    float2 f2 = *(const float2*)&fFw[j * 132 + c0];
    float e0 = f2.x > 0.f ? f2.x : __expf(f2.x) - 1.f;
    float e1 = f2.y > 0.f ? f2.y : __expf(f2.y) - 1.f;
    lf0 += w9r[j] * e0;
    lf1 += w9r[j] * e1;
  }
  float2 xv = *(const float2*)(xt + (size_t)pos * CCH + c0);
  float y0 = lf0 + xv.x, y1 = lf1 + xv.y;
  *(float2*)(Y + (size_t)pos * CCH + c0) = make_float2(y0, y1);
  float s1 = y0 + y1, s2 = y0 * y0 + y1 * y1;
  #pragma unroll
  for (int mm = 1; mm <= 8; mm <<= 1) { s1 += __shfl_xor(s1, mm); s2 += __shfl_xor(s2, mm); }
  if ((l & 15) == 0) {
    gnPart[(size_t)pos * 8 + g * 2]     = s1;
    gnPart[(size_t)pos * 8 + g * 2 + 1] = s2;
  }
}

// ---------------- K5: GN stats -> per (b,c) affine a,d ----------------
__global__ void k_gnstats(const float* __restrict__ gnPart,
                          const float* __restrict__ gn_g, const float* __restrict__ gn_b,
                          float* __restrict__ gnA, float* __restrict__ gnD) {
  int bg = blockIdx.x; int b = bg >> 2, g = bg & 3;
  int tid = threadIdx.x;
  float s1 = 0.f, s2 = 0.f;
  for (int r = tid; r < NPTS; r += 256) {
    const float* p = gnPart + (size_t)(b * NPTS + r) * 8 + g * 2;
    s1 += p[0]; s2 += p[1];
  }
  __shared__ float r1[256], r2[256];
  r1[tid] = s1; r2[tid] = s2;
  __syncthreads();
  for (int off = 128; off > 0; off >>= 1) {
    if (tid < off) { r1[tid] += r1[tid + off]; r2[tid] += r2[tid + off]; }
    __syncthreads();
  }
  __shared__ float muS, rsS;
  if (tid == 0) {
    float mu = r1[0] * (1.f / 131072.f);
    float var = r2[0] * (1.f / 131072.f) - mu * mu;
    muS = mu; rsS = 1.f / sqrtf(var + 1e-5f);
  }
  __syncthreads();
  if (tid < 32) {
    int c = g * 32 + tid;
    float a = rsS * gn_g[c];
    gnA[b * 128 + c] = a;
    gnD[b * 128 + c] = gn_b[c] - muS * a;
  }
}

// ---------------- K5b: fold GN affine into conv weights per batch ----------------
__global__ void k_fold(const float* __restrict__ conv_w, const float* __restrict__ conv_b,
                       const float* __restrict__ gnA, const float* __restrict__ gnD,
                       float* __restrict__ Wp, float* __restrict__ biasp) {
  int b = blockIdx.x; int tid = threadIdx.x;
  __shared__ float dS[128], aS[128];
  if (tid < 128) { dS[tid] = gnD[b * 128 + tid]; aS[tid] = gnA[b * 128 + tid]; }
  __syncthreads();
  for (int f = tid; f < 16384; f += 256)
    Wp[(size_t)b * 16384 + f] = conv_w[f] * aS[f & 127];
  if (tid < 128) {
    float s = conv_b[tid];
    for (int c = 0; c < 128; c++) s += conv_w[tid * 128 + c] * dS[c];
    biasp[b * 128 + tid] = s;
  }
}

// ---------------- K6: conv GEMM on raw y + BN partial sums ----------------
__launch_bounds__(256)
__global__ void k_conv(const float* __restrict__ Y, const float* __restrict__ Wp,
                       const float* __restrict__ biasp, float* __restrict__ zpre,
                       float* __restrict__ bnSum, float* __restrict__ bnSq) {
  __shared__ __align__(16) float Ys[64 * 132];
  __shared__ __align__(16) float Ws[64 * 132];
  int tid = threadIdx.x;
  int tx = tid & 15, ty = tid >> 4;
  int n0 = blockIdx.x * 64, o0 = blockIdx.y * 64, b = blockIdx.z;
  #pragma unroll
  for (int i = 0; i < 8; i++) {
    int flat = tid + i * 256; int r = flat >> 5, c4 = flat & 31;
    *(float4*)&Ys[r * 132 + c4 * 4] = *(const float4*)&Y[(size_t)((b << 12) + n0 + r) * CCH + c4 * 4];
    *(float4*)&Ws[r * 132 + c4 * 4] = *(const float4*)&Wp[(size_t)b * 16384 + (size_t)(o0 + r) * 128 + c4 * 4];
  }
  __syncthreads();
  float acc[4][4] = {};
  #pragma unroll 2
  for (int kq = 0; kq < 32; kq++) {
    float4 wa[4], yb[4];
    #pragma unroll
    for (int i = 0; i < 4; i++) wa[i] = *(const float4*)&Ws[(ty * 4 + i) * 132 + kq * 4];
    #pragma unroll
    for (int j = 0; j < 4; j++) yb[j] = *(const float4*)&Ys[(tx + 16 * j) * 132 + kq * 4];
    #pragma unroll
    for (int i = 0; i < 4; i++)
      #pragma unroll
      for (int j = 0; j < 4; j++)
        acc[i][j] += wa[i].x * yb[j].x + wa[i].y * yb[j].y + wa[i].z * yb[j].z + wa[i].w * yb[j].w;
  }
  #pragma unroll
  for (int i = 0; i < 4; i++) {
    int o = o0 + ty * 4 + i;
    float bias = biasp[b * 128 + o];
    float p1 = 0.f, p2 = 0.f;
    #pragma unroll
    for (int j = 0; j < 4; j++) {
      float z = acc[i][j] + bias;
      zpre[(((size_t)((b << 7) + o)) << 12) + n0 + tx + 16 * j] = z;
      p1 += z; p2 += z * z;
    }
    #pragma unroll
    for (int mm = 1; mm <= 8; mm <<= 1) { p1 += __shfl_xor(p1, mm); p2 += __shfl_xor(p2, mm); }
    if (tx == 0) { atomicAdd(&bnSum[o], p1); atomicAdd(&bnSq[o], p2); }
  }
}

// ---------------- K7a: BN finalize ----------------
__global__ void k_bnfin(const float* __restrict__ bnSum, const float* __restrict__ bnSq,
                        const float* __restrict__ bn_g, const float* __restrict__ bn_b,
                        float* __restrict__ bnScale, float* __restrict__ bnShift) {
  int o = threadIdx.x;
  float m = bnSum[o] * (1.f / 16384.f);
  float v = bnSq[o] * (1.f / 16384.f) - m * m;
  float sc = bn_g[o] / sqrtf(v + 1e-5f);
  bnScale[o] = sc;
  bnShift[o] = bn_b[o] - m * sc;
}

// ---------------- K7b: normalize + ReLU -> d_out ----------------
__global__ void k_final(const float* __restrict__ zpre, const float* __restrict__ bnScale,
                        const float* __restrict__ bnShift, float* __restrict__ out) {
  int i4 = blockIdx.x * 256 + threadIdx.x;
  int e = i4 * 4;
  int o = (e >> 12) & 127;
  float4 z = *(const float4*)&zpre[e];
  float sc = bnScale[o], sh = bnShift[o];
  float4 r;
  r.x = fmaxf(fmaf(z.x, sc, sh), 0.f);
  r.y = fmaxf(fmaf(z.y, sc, sh), 0.f);
  r.z = fmaxf(fmaf(z.z, sc, sh), 0.f);
  r.w = fmaxf(fmaf(z.w, sc, sh), 0.f);
  *(float4*)&out[e] = r;
}

extern "C" void kernel_launch(void* const* d_in, const int* in_sizes, int n_in,
                              void* d_out, int out_size, void* d_ws, size_t ws_size,
                              hipStream_t stream) {
  const float* features = (const float*)d_in[0];
  const float* w_lin  = (const float*)d_in[1];
  const float* b_lin  = (const float*)d_in[2];
  const float* w_aw   = (const float*)d_in[3];
  const float* b_aw   = (const float*)d_in[4];
  const float* gn_g   = (const float*)d_in[5];
  const float* gn_b   = (const float*)d_in[6];
  const float* conv_w = (const float*)d_in[7];
  const float* conv_b = (const float*)d_in[8];
  const float* bn_g   = (const float*)d_in[9];
  const float* bn_b   = (const float*)d_in[10];

  float* ws    = (float*)d_ws;
  float* xt    = ws + OFF_XT;
  float* xxp   = ws + OFF_XX;
  __hip_bfloat16* xhip = (__hip_bfloat16*)(ws + OFF_XHI);
  int*   idxp  = (int*)(ws + OFF_IDX);
  float* Op    = ws + OFF_O;
  float* candp = ws + OFF_O;   // alias: dead before k_linear writes O
  float* Yp    = ws + OFF_Y;
  float* gnp   = ws + OFF_GNP;
  float* gnA   = ws + OFF_GNA;
  float* gnD   = ws + OFF_GND;
  float* Wp    = ws + OFF_WP;
  float* biasp = ws + OFF_BIASP;
  float* bnSum = ws + OFF_BNSUM;
  float* bnSq  = ws + OFF_BNSQ;
  float* bnSc  = ws + OFF_BNSC;
  float* bnSh  = ws + OFF_BNSH;
  float* zpre  = xt; // alias: xt dead after k_attn

  hipMemsetAsync(xxp, 0, NPTS * BB * sizeof(float), stream);
  hipMemsetAsync(bnSum, 0, 256 * sizeof(float), stream); // bnSum + bnSq contiguous

  k_transpose<<<dim3(128, 4, 4), dim3(32, 32), 0, stream>>>(features, xt, xhip, xxp);
  k_knn<<<dim3(128, 4), 256, 0, stream>>>((const short*)xhip, xxp, candp);
  k_rerank<<<4096, 256, 0, stream>>>(candp, xt, xxp, idxp);
  k_linear<<<dim3(256, 5), 256, 0, stream>>>(xt, w_lin, b_lin, w_aw, b_aw, Op);
  k_attn<<<4096, 256, 0, stream>>>(Op, idxp, xt, Yp, gnp);
  k_gnstats<<<16, 256, 0, stream>>>(gnp, gn_g, gn_b, gnA, gnD);
  k_fold<<<4, 256, 0, stream>>>(conv_w, conv_b, gnA, gnD, Wp, biasp);
  k_conv<<<dim3(64, 2, 4), 256, 0, stream>>>(Yp, Wp, biasp, zpre, bnSum, bnSq);
  k_bnfin<<<1, 128, 0, stream>>>(bnSum, bnSq, bn_g, bn_b, bnSc, bnSh);
  k_final<<<2048, 256, 0, stream>>>(zpre, bnSc, bnSh, (float*)d_out);
}